// Round 10
// baseline (1410.728 us; speedup 1.0000x reference)
//
#include <hip/hip_runtime.h>
#include <math.h>

#define HD 128  // hidden dim

typedef __bf16 bf16x8 __attribute__((ext_vector_type(8)));
typedef unsigned short u16x8 __attribute__((ext_vector_type(8)));
typedef float f32x4 __attribute__((ext_vector_type(4)));

__device__ __forceinline__ unsigned short f2bf(float f) {
    unsigned u = __float_as_uint(f);
    unsigned r = u + 0x7FFFu + ((u >> 16) & 1u);   // RTN-even
    return (unsigned short)(r >> 16);
}

// load 2 consecutive feats at element offset off; xbf: X is bf16
__device__ __forceinline__ float2 ldrow2(const void* X, size_t off, int xbf) {
    if (xbf) {
        unsigned u = *(const unsigned*)((const unsigned short*)X + off);
        return make_float2(__uint_as_float((u & 0xffffu) << 16),
                           __uint_as_float((u >> 16) << 16));
    }
    return *(const float2*)((const float*)X + off);
}

// ---------------------------------------------------------------- weight convert
#define MAXW 32
struct WDesc { const float* src; unsigned short* dst; int K, N, Kpad, tr; };
struct WBatch { WDesc d[MAXW]; };

__global__ void convert_weights(WBatch wb)
{
    WDesc d = wb.d[blockIdx.y];
    long total = (long)d.N * d.Kpad;
    long i = (long)blockIdx.x * 256 + threadIdx.x;
    if (i >= total) return;
    int n = (int)(i / d.Kpad), k = (int)(i % d.Kpad);
    float v = 0.f;
    if (k < d.K) v = d.tr ? d.src[(size_t)k * d.N + n] : d.src[(size_t)n * d.K + k];
    d.dst[i] = f2bf(v);
}

// ---------------------------------------------------------------- MFMA GEMM
// C[M,N] = act( [A0|A1|A2] @ W + bias ), W as bf16 WT[N][Kpad].
// Per-segment A dtype (dt=1: bf16 rows, staged by straight copy; dt=0: fp32->bf16).
// act: 0 none, 1 lrelu, 2 sigmoid, 3 gate: C = z*G1 + (1-z)*G2, z=sigmoid(v).
// obf: write C as bf16. 2-phase double-buffered staging, one s_barrier/tile,
// only lgkmcnt drained (global loads stay in flight).
// C/D: col=lane&15, row=(lane>>4)*4+reg  [m89-verified].
__global__ __launch_bounds__(256)
void gemm_mfma(const void* __restrict__ A0, const void* __restrict__ A1,
               const void* __restrict__ A2, int K0, int K1, int K2,
               int lda0, int lda1, int lda2, int dt0, int dt1, int dt2,
               const unsigned short* __restrict__ WT, int Kpad,
               const float* __restrict__ bias, void* __restrict__ Cv,
               int M, int N, int act, int obf,
               const float* __restrict__ G1, const float* __restrict__ G2)
{
    __shared__ __align__(16) unsigned short sA[2][64][40];
    __shared__ __align__(16) unsigned short sW[2][128][40];

    const int tid = threadIdx.x;
    const int lane = tid & 63, w = tid >> 6;
    const int mBase = blockIdx.x * 64;
    const int nBase = blockIdx.y * 128;
    const int Ktot = K0 + K1 + K2;
    const int colb = w * 32;
    const int c16 = lane & 15, g = lane >> 4;

    f32x4 acc[4][2];
#pragma unroll
    for (int i = 0; i < 4; ++i)
#pragma unroll
        for (int j = 0; j < 2; ++j) acc[i][j] = (f32x4){0.f, 0.f, 0.f, 0.f};

    const int kTiles = (Ktot + 31) / 32;

    auto loadTile = [&](int kt, float f[8], u16x8& ha, int& isbf, u16x8& h0, u16x8& h1) {
        const int k0g = kt * 32;
        const void* Ab; int lda, kloc, segK;
        if (k0g < K0)           { Ab = A0; lda = lda0; kloc = k0g;           segK = K0; isbf = dt0; }
        else if (k0g < K0 + K1) { Ab = A1; lda = lda1; kloc = k0g - K0;      segK = K1; isbf = dt1; }
        else                    { Ab = A2; lda = lda2; kloc = k0g - K0 - K1; segK = K2; isbf = dt2; }
        int row = tid >> 2, kq = (tid & 3) * 8;
        int gr = mBase + row;
        if (isbf) {
            u16x8 z;
#pragma unroll
            for (int i = 0; i < 8; ++i) z[i] = 0;
            ha = (gr < M && kloc + kq + 8 <= segK)
                 ? *(const u16x8*)((const unsigned short*)Ab + (size_t)gr * lda + kloc + kq)
                 : z;
        } else {
            const float* Af = (const float*)Ab;
            if (gr < M && ((lda & 3) == 0) && (kloc + kq + 8 <= segK)) {
                const float* ap = Af + (size_t)gr * lda + kloc + kq;
                float4 v0 = *(const float4*)ap, v1 = *(const float4*)(ap + 4);
                f[0] = v0.x; f[1] = v0.y; f[2] = v0.z; f[3] = v0.w;
                f[4] = v1.x; f[5] = v1.y; f[6] = v1.z; f[7] = v1.w;
            } else {
#pragma unroll
                for (int i = 0; i < 8; ++i) {
                    int kk = kloc + kq + i;
                    f[i] = (gr < M && kk < segK) ? Af[(size_t)gr * lda + kk] : 0.f;
                }
            }
        }
        int col = tid >> 1, kh = (tid & 1) * 16;
        const unsigned short* wp = WT + (size_t)(nBase + col) * Kpad + k0g + kh;
        h0 = *(const u16x8*)wp;
        h1 = *(const u16x8*)(wp + 8);
    };
    auto stageWrite = [&](int buf, int isbf, const float f[8], u16x8 ha, u16x8 h0, u16x8 h1) {
        int row = tid >> 2, kq = (tid & 3) * 8;
        u16x8 h;
        if (isbf) h = ha;
        else {
#pragma unroll
            for (int i = 0; i < 8; ++i) h[i] = f2bf(f[i]);
        }
        *(u16x8*)&sA[buf][row][kq] = h;
        int col = tid >> 1, kh = (tid & 1) * 16;
        *(u16x8*)&sW[buf][col][kh] = h0;
        *(u16x8*)&sW[buf][col][kh + 8] = h1;
    };
    auto compute = [&](int buf) {
        bf16x8 bfr0 = __builtin_bit_cast(bf16x8, *(const u16x8*)&sW[buf][colb + c16][g * 8]);
        bf16x8 bfr1 = __builtin_bit_cast(bf16x8, *(const u16x8*)&sW[buf][colb + 16 + c16][g * 8]);
#pragma unroll
        for (int rf = 0; rf < 4; ++rf) {
            bf16x8 af = __builtin_bit_cast(bf16x8, *(const u16x8*)&sA[buf][rf * 16 + c16][g * 8]);
            acc[rf][0] = __builtin_amdgcn_mfma_f32_16x16x32_bf16(af, bfr0, acc[rf][0], 0, 0, 0);
            acc[rf][1] = __builtin_amdgcn_mfma_f32_16x16x32_bf16(af, bfr1, acc[rf][1], 0, 0, 0);
        }
    };

    // prologue: stage tile 0, prefetch tile 1
    float fN[8]; u16x8 haN, hN0, hN1; int bfN = 0;
    {
        float fC[8]; u16x8 haC, hC0, hC1; int bfC;
        loadTile(0, fC, haC, bfC, hC0, hC1);
        stageWrite(0, bfC, fC, haC, hC0, hC1);
        if (kTiles > 1) loadTile(1, fN, haN, bfN, hN0, hN1);
    }
    asm volatile("s_waitcnt lgkmcnt(0)" ::: "memory");
    __builtin_amdgcn_s_barrier();

    int cur = 0;
#pragma unroll 2
    for (int kt = 0; kt < kTiles; ++kt) {
        float fP[8]; u16x8 haP, hP0, hP1; int bfP = 0;
        const bool pf = (kt + 2 < kTiles);
        if (pf) loadTile(kt + 2, fP, haP, bfP, hP0, hP1);   // issue early
        compute(cur);
        if (kt + 1 < kTiles) stageWrite(cur ^ 1, bfN, fN, haN, hN0, hN1);
        asm volatile("s_waitcnt lgkmcnt(0)" ::: "memory");
        __builtin_amdgcn_s_barrier();
        if (pf) {
#pragma unroll
            for (int i = 0; i < 8; ++i) fN[i] = fP[i];
            haN = haP; hN0 = hP0; hN1 = hP1; bfN = bfP;
        }
        cur ^= 1;
    }

    // ---- epilogue
#pragma unroll
    for (int cf = 0; cf < 2; ++cf) {
        int col = nBase + colb + cf * 16 + c16;
        float bb = bias ? bias[col] : 0.f;
#pragma unroll
        for (int rf = 0; rf < 4; ++rf) {
            int r0 = mBase + rf * 16 + g * 4;
#pragma unroll
            for (int r = 0; r < 4; ++r) {
                int gr = r0 + r;
                if (gr >= M) continue;
                size_t o = (size_t)gr * N + col;
                float v = acc[rf][cf][r] + bb;
                if (act == 1) v = v > 0.f ? v : 0.1f * v;
                else if (act == 2) v = 1.f / (1.f + expf(-v));
                else if (act == 3) {
                    float z = 1.f / (1.f + expf(-v));
                    v = z * G1[o] + (1.f - z) * G2[o];
                }
                if (obf) ((unsigned short*)Cv)[o] = f2bf(v);
                else     ((float*)Cv)[o] = v;
            }
        }
    }
}

// ---------------------------------------------------------------- CSR build
__global__ void hist_k(int* __restrict__ cnt, const int* __restrict__ dst, int E)
{
    int i = blockIdx.x * 256 + threadIdx.x;
    if (i < E) atomicAdd(&cnt[dst[i]], 1);
}

#define SCB 4096

__global__ __launch_bounds__(256)
void scan_sums(const int* __restrict__ cnt, int n, int* __restrict__ bsum)
{
    __shared__ int red[256];
    int t = threadIdx.x;
    int base = blockIdx.x * SCB + t * 16;
    int s = 0;
#pragma unroll
    for (int i = 0; i < 16; ++i) { int idx = base + i; if (idx < n) s += cnt[idx]; }
    red[t] = s; __syncthreads();
    for (int st = 128; st > 0; st >>= 1) {
        if (t < st) red[t] += red[t + st];
        __syncthreads();
    }
    if (t == 0) bsum[blockIdx.x] = red[0];
}

__global__ void scan_bsum(int* __restrict__ bsum, int nb)
{
    if (threadIdx.x == 0) {
        int run = 0;
        for (int i = 0; i < nb; ++i) { int v = bsum[i]; bsum[i] = run; run += v; }
    }
}

__global__ __launch_bounds__(256)
void scan_write(const int* __restrict__ cnt, int n, const int* __restrict__ bsum,
                int* __restrict__ rp)
{
    __shared__ int a0[256], a1[256];
    int t = threadIdx.x;
    int base = blockIdx.x * SCB + t * 16;
    int v[16]; int s = 0;
#pragma unroll
    for (int i = 0; i < 16; ++i) { int idx = base + i; v[i] = (idx < n) ? cnt[idx] : 0; s += v[i]; }
    a0[t] = s; __syncthreads();
    int* cur = a0; int* nxt = a1;
    for (int st = 1; st < 256; st <<= 1) {
        int val = cur[t] + ((t >= st) ? cur[t - st] : 0);
        nxt[t] = val; __syncthreads();
        int* tmp = cur; cur = nxt; nxt = tmp;
    }
    int run = bsum[blockIdx.x] + (t > 0 ? cur[t - 1] : 0);
#pragma unroll
    for (int i = 0; i < 16; ++i) {
        int idx = base + i;
        if (idx < n) {
            rp[idx] = run; run += v[i];
            if (idx == n - 1) rp[n] = run;
        }
    }
}

__global__ void fill_k(int* __restrict__ eidx, int* __restrict__ cursor,
                       const int* __restrict__ dst, int E)
{
    int i = blockIdx.x * 256 + threadIdx.x;
    if (i < E) eidx[atomicAdd(&cursor[dst[i]], 1)] = i;
}

// ---------------------------------------------------------------- CSR gather
// One wave per destination row; lane covers 2 feats.
// mode 0: w=1   1: w=wattr[e]   2: w=1/deg   3: w=softmax(6-wattr)[e]
// xbf/obf: X / out stored as bf16. Edge loop unrolled 4-deep.
__global__ __launch_bounds__(256)
void seg_gather(void* __restrict__ out, const void* __restrict__ X,
                const int* __restrict__ rowptr, const int* __restrict__ eidx,
                const int* __restrict__ src, const float* __restrict__ wattr,
                const float* __restrict__ bias, int n, int ostride, int ooff,
                int act, int mode, int xbf, int obf)
{
    int d = blockIdx.x * 4 + (threadIdx.x >> 6);
    if (d >= n) return;
    int lane = threadIdx.x & 63;
    int lo = rowptr[d], hi = rowptr[d + 1];
    float w0 = 1.f, mx = 0.f, iden = 0.f;
    if (mode == 2) w0 = (hi > lo) ? 1.f / (float)(hi - lo) : 0.f;
    if (mode == 3) {
        float mxl = -1e30f;
        for (int base = lo; base < hi; base += 64) {
            int i = base + lane;
            if (i < hi) mxl = fmaxf(mxl, 6.f - wattr[eidx[i]]);
        }
#pragma unroll
        for (int o = 32; o; o >>= 1) mxl = fmaxf(mxl, __shfl_xor(mxl, o));
        mx = mxl;
        float dl = 0.f;
        for (int base = lo; base < hi; base += 64) {
            int i = base + lane;
            if (i < hi) dl += expf(6.f - wattr[eidx[i]] - mx);
        }
#pragma unroll
        for (int o = 32; o; o >>= 1) dl += __shfl_xor(dl, o);
        iden = 1.f / dl;
    }

    float ax = 0.f, ay = 0.f;
    int i = lo;
    for (; i + 4 <= hi; i += 4) {
        int e0 = eidx[i], e1 = eidx[i + 1], e2 = eidx[i + 2], e3 = eidx[i + 3];
        int s0 = src ? src[e0] : e0, s1 = src ? src[e1] : e1;
        int s2 = src ? src[e2] : e2, s3 = src ? src[e3] : e3;
        float w0v, w1v, w2v, w3v;
        if (mode == 0) { w0v = w1v = w2v = w3v = 1.f; }
        else if (mode == 1) { w0v = wattr[e0]; w1v = wattr[e1]; w2v = wattr[e2]; w3v = wattr[e3]; }
        else if (mode == 2) { w0v = w1v = w2v = w3v = w0; }
        else {
            w0v = expf(6.f - wattr[e0] - mx) * iden;
            w1v = expf(6.f - wattr[e1] - mx) * iden;
            w2v = expf(6.f - wattr[e2] - mx) * iden;
            w3v = expf(6.f - wattr[e3] - mx) * iden;
        }
        float2 v0 = ldrow2(X, (size_t)s0 * HD + 2 * lane, xbf);
        float2 v1 = ldrow2(X, (size_t)s1 * HD + 2 * lane, xbf);
        float2 v2 = ldrow2(X, (size_t)s2 * HD + 2 * lane, xbf);
        float2 v3 = ldrow2(X, (size_t)s3 * HD + 2 * lane, xbf);
        ax += w0v * v0.x + w1v * v1.x + w2v * v2.x + w3v * v3.x;
        ay += w0v * v0.y + w1v * v1.y + w2v * v2.y + w3v * v3.y;
    }
    for (; i < hi; ++i) {
        int e = eidx[i];
        int s = src ? src[e] : e;
        float w;
        if (mode == 0) w = 1.f;
        else if (mode == 1) w = wattr[e];
        else if (mode == 2) w = w0;
        else w = expf(6.f - wattr[e] - mx) * iden;
        float2 v = ldrow2(X, (size_t)s * HD + 2 * lane, xbf);
        ax += w * v.x; ay += w * v.y;
    }
    if (bias) { float2 b = *(const float2*)(bias + 2 * lane); ax += b.x; ay += b.y; }
    if (act == 1) { ax = ax > 0.f ? ax : 0.1f * ax; ay = ay > 0.f ? ay : 0.1f * ay; }
    size_t o = (size_t)d * ostride + ooff + 2 * lane;
    if (obf) {
        unsigned u = (unsigned)f2bf(ax) | ((unsigned)f2bf(ay) << 16);
        *(unsigned*)((unsigned short*)out + o) = u;
    } else {
        *(float2*)((float*)out + o) = make_float2(ax, ay);
    }
}

// ---------------------------------------------------------------- fused segment softmax
__global__ __launch_bounds__(256)
void seg_softmax_csr(float* __restrict__ sc, const int* __restrict__ rowptr,
                     const int* __restrict__ eidx, int n)
{
    int d = blockIdx.x * 4 + (threadIdx.x >> 6);
    if (d >= n) return;
    int lane = threadIdx.x & 63;
    int lo = rowptr[d], hi = rowptr[d + 1];
    float mxl = -1e30f;
    for (int i = lo + lane; i < hi; i += 64) mxl = fmaxf(mxl, sc[eidx[i]]);
#pragma unroll
    for (int o = 32; o; o >>= 1) mxl = fmaxf(mxl, __shfl_xor(mxl, o));
    float dl = 0.f;
    for (int i = lo + lane; i < hi; i += 64) dl += expf(sc[eidx[i]] - mxl);
#pragma unroll
    for (int o = 32; o; o >>= 1) dl += __shfl_xor(dl, o);
    float iden = 1.f / dl;
    for (int i = lo + lane; i < hi; i += 64) {
        int v = eidx[i];
        sc[v] = expf(sc[v] - mxl) * iden;
    }
}

// ---------------------------------------------------------------- misc kernels
__global__ void gather128(float* __restrict__ out, const float* __restrict__ in,
                          const int* __restrict__ idx, int n)
{
    long i = (long)blockIdx.x * 256 + threadIdx.x;
    if (i >= (long)n * HD) return;
    int r = (int)(i >> 7), f = (int)(i & 127);
    out[i] = in[(size_t)idx[r] * HD + f];
}

__global__ void gru_gate(float* __restrict__ h, const float* __restrict__ gi,
                         const float* __restrict__ gh, int M)
{
    long i = (long)blockIdx.x * 256 + threadIdx.x;
    if (i >= (long)M * HD) return;
    int row = (int)(i >> 7), f = (int)(i & 127);
    size_t o = (size_t)row * 384 + f;
    float r = 1.f / (1.f + expf(-(gi[o] + gh[o])));
    float z = 1.f / (1.f + expf(-(gi[o + 128] + gh[o + 128])));
    float n = tanhf(gi[o + 256] + r * gh[o + 256]);
    h[i] = (1.f - z) * n + z * h[i];
}

__global__ void dot_score(float* __restrict__ sc, const float* __restrict__ kb,
                          const float* __restrict__ qs, const int* __restrict__ batch, int n)
{
    int v = blockIdx.x * 256 + threadIdx.x;
    if (v >= n) return;
    const float4* a = (const float4*)(kb + (size_t)v * HD);
    const float4* q = (const float4*)(qs + (size_t)batch[v] * HD);
    float acc = 0.f;
#pragma unroll
    for (int i = 0; i < 32; ++i) {
        float4 x = a[i], y = q[i];
        acc += x.x * y.x + x.y * y.y + x.z * y.z + x.w * y.w;
    }
    sc[v] = acc * 0.08838834764831843f;  // 1/sqrt(128)
}

__global__ void pdist_k(float* __restrict__ out, const float* __restrict__ A,
                        const float* __restrict__ Bm, const int* __restrict__ ia,
                        const int* __restrict__ ib, int P)
{
    int p = blockIdx.x * 256 + threadIdx.x;
    if (p >= P) return;
    const float4* a = (const float4*)(A + (size_t)ia[p] * HD);
    const float4* b = (const float4*)(Bm + (size_t)ib[p] * HD);
    float acc = 0.f;
#pragma unroll
    for (int i = 0; i < 32; ++i) {
        float4 x = a[i], y = b[i];
        float d0 = x.x - y.x + 1e-6f, d1 = x.y - y.y + 1e-6f;
        float d2 = x.z - y.z + 1e-6f, d3 = x.w - y.w + 1e-6f;
        acc += d0 * d0 + d1 * d1 + d2 * d2 + d3 * d3;
    }
    out[p] = sqrtf(acc);
}

// ---------------------------------------------------------------- host

static inline unsigned gupd(size_t n) { return (unsigned)((n + 255) / 256); }
static inline unsigned gup4(size_t n) { return (unsigned)((n + 3) / 4); }

struct WArena { unsigned short* p; int Kpad; };

static void gemmX(hipStream_t st, const void* A0, int K0, int dt0,
                  const void* A1, int K1, int dt1,
                  const void* A2, int K2, int dt2,
                  WArena wa, const float* bias, void* C, int M, int N,
                  int act, int obf,
                  const float* G1 = nullptr, const float* G2 = nullptr)
{
    dim3 g((M + 63) / 64, N / 128);
    hipLaunchKernelGGL(gemm_mfma, g, dim3(256), 0, st, A0, A1, A2, K0, K1, K2,
                       K0, K1, K2, dt0, dt1, dt2, wa.p, wa.Kpad, bias, C, M, N,
                       act, obf, G1, G2);
}
static void gemm1(hipStream_t st, const void* A, int K, int dt, WArena wa,
                  const float* bias, void* C, int M, int N, int act, int obf)
{ gemmX(st, A, K, dt, nullptr, 0, 0, nullptr, 0, 0, wa, bias, C, M, N, act, obf); }

extern "C" void kernel_launch(void* const* d_in, const int* in_sizes, int n_in,
                              void* d_out, int out_size, void* d_ws, size_t ws_size,
                              hipStream_t stream)
{
    (void)n_in; (void)out_size;
    const float* vert_x  = (const float*)d_in[0];
    const float* site_x  = (const float*)d_in[1];
    const float* masf_x  = (const float*)d_in[2];
    const float* prot_ea = (const float*)d_in[3];
    const float* prom_ea = (const float*)d_in[4];
    const int* vert_src = (const int*)d_in[5];
    const int* vert_dst = (const int*)d_in[6];
    const int* vbatch   = (const int*)d_in[7];
    const int* comp_src = (const int*)d_in[8];
    const int* comp_dst = (const int*)d_in[9];
    const int* site_src = (const int*)d_in[10];
    const int* site_dst = (const int*)d_in[11];
    const int* masf_src = (const int*)d_in[12];
    const int* masf_dst = (const int*)d_in[13];
    const int* prot_src = (const int*)d_in[14];
    const int* prot_dst = (const int*)d_in[15];
    const int* prom_src = (const int*)d_in[16];
    const int* prom_dst = (const int*)d_in[17];
    const int* anch_src = (const int*)d_in[18];
    const int* anch_dst = (const int*)d_in[19];
    const int* ag_a = (const int*)d_in[20];
    const int* ag_g = (const int*)d_in[21];
    const int* aa0  = (const int*)d_in[22];
    const int* aa1  = (const int*)d_in[23];
    const int* gg0  = (const int*)d_in[24];
    const int* gg1  = (const int*)d_in[25];
    const float* W_emb = (const float*)d_in[26];
    const float* b_emb = (const float*)d_in[27];
    const float* gW_main = (const float*)d_in[28];
    const float* gW_s2m  = (const float*)d_in[29];
    const float* gW_gm   = (const float*)d_in[30];
    const float* gb_gm   = (const float*)d_in[31];
    const float* gW_q    = (const float*)d_in[32];
    const float* gW_k    = (const float*)d_in[33];
    const float* gW_mrg  = (const float*)d_in[34];
    const float* gW_gs   = (const float*)d_in[35];
    const float* gb_gs   = (const float*)d_in[36];
    const float* gm_Wih = (const float*)d_in[37];
    const float* gm_Whh = (const float*)d_in[38];
    const float* gm_bih = (const float*)d_in[39];
    const float* gm_bhh = (const float*)d_in[40];
    const float* gs_Wih = (const float*)d_in[41];
    const float* gs_Whh = (const float*)d_in[42];
    const float* gs_bih = (const float*)d_in[43];
    const float* gs_bhh = (const float*)d_in[44];
    const float* W_s0 = (const float*)d_in[45];
    const float* b_s0 = (const float*)d_in[46];
    const float* W_s1 = (const float*)d_in[47];
    const float* b_s1 = (const float*)d_in[48];
    const float* W_so = (const float*)d_in[49];
    const float* b_so = (const float*)d_in[50];
    const float* W_m0 = (const float*)d_in[51];
    const float* b_m0 = (const float*)d_in[52];
    const float* W_m1 = (const float*)d_in[53];
    const float* b_m1 = (const float*)d_in[54];
    const float* W_mo = (const float*)d_in[55];
    const float* b_mo = (const float*)d_in[56];
    const float* W_a0 = (const float*)d_in[57];
    const float* b_a0 = (const float*)d_in[58];
    const float* W_a1 = (const float*)d_in[59];
    const float* b_a1 = (const float*)d_in[60];
    const float* W_ao = (const float*)d_in[61];
    const float* b_ao = (const float*)d_in[62];
    const float* W_ds = (const float*)d_in[63];
    const float* b_ds = (const float*)d_in[64];
    const float* W_dc = (const float*)d_in[65];
    const float* b_dc = (const float*)d_in[66];

    const int B = 256, NG = 4000, NA = 10000, Ns = 80000, Nm = 80000;
    const int Nv = in_sizes[7];
    const int FV = in_sizes[0] / Nv;
    const int Fs = in_sizes[1] / Ns;
    const int Fm = in_sizes[2] / Nm;
    const int Ev = in_sizes[5], Ec = in_sizes[8], Es = in_sizes[10], Em = in_sizes[12];
    const int Ep = in_sizes[14], Ea = in_sizes[18];
    const int Pag = in_sizes[20], Paa = in_sizes[22], Pgg = in_sizes[24];
    const int D = in_sizes[28] / (HD * HD);

    // ---- workspace layout (floats; bf16 buffers reinterpret their region) --
    float* ws = (float*)d_ws;
    size_t off = 0;
    auto take = [&](size_t n) { size_t o = off; off += n; return o; };
    float* vert  = ws + take((size_t)Nv * HD);
    float* supe  = ws + take((size_t)B * HD);
    float* qsup  = ws + take((size_t)B * HD);
    float* pool  = ws + take((size_t)B * HD);
    float* msup  = ws + take((size_t)B * HD);
    float* zsup  = ws + take((size_t)B * HD);
    float* gis   = ws + take((size_t)B * 3 * HD);
    float* ghs   = ws + take((size_t)B * 3 * HD);
    float* tsml  = ws + take((size_t)B * HD);
    unsigned short* grp_h    = (unsigned short*)(ws + take((size_t)NG * HD));
    unsigned short* site_o_h = (unsigned short*)(ws + take((size_t)Ns * HD));
    unsigned short* masf_o_h = (unsigned short*)(ws + take((size_t)Nm * HD));
    unsigned short* anch_h   = (unsigned short*)(ws + take((size_t)NA * 2 * HD));
    unsigned short* ah1_h    = (unsigned short*)(ws + take((size_t)NA * HD));
    unsigned short* ah2_h    = (unsigned short*)(ws + take((size_t)NA * HD));
    unsigned short* axw_h    = (unsigned short*)(ws + take((size_t)NA * HD));
    unsigned short* aout_h   = (unsigned short*)(ws + take((size_t)NA * HD));
    float* pa    = ws + take((size_t)NA * HD);
    float* pg    = ws + take((size_t)NG * HD);
    float* score = ws + take((size_t)Nv);
    const size_t NvH = (size_t)Nv * HD, NsH = (size_t)Ns * HD;
    float* T = ws + take(3 * NsH);   // shared temp region (fp32 GWM temps + bf16 conv temps)

    // ---- CSR arrays (ints), concatenated layout --------------------------
    const int nN[8] = {Nv, NG, Ns, Nm, NA, NA, NA, B};
    const int nE[8] = {Ev, Ec, Es, Em, Ep, Ep, Ea, Nv};
    const int* dsts[8] = {vert_dst, comp_dst, site_dst, masf_dst,
                          prot_dst, prom_dst, anch_dst, vbatch};
    int baseN[9], baseE[9];
    baseN[0] = 0; baseE[0] = 0;
    for (int g = 0; g < 8; ++g) { baseN[g + 1] = baseN[g] + nN[g]; baseE[g + 1] = baseE[g] + nE[g]; }
    const int totN = baseN[8], totE = baseE[8];

    int* ib = (int*)(ws + off);
    size_t ioff = 0;
    auto taki = [&](size_t n) { size_t o = ioff; ioff += n; return o; };
    int* cnt_all = ib + taki((size_t)totN);
    int* rp_all  = ib + taki((size_t)totN + 1);
    int* cur_all = ib + taki((size_t)totN);
    int* ei_all  = ib + taki((size_t)totE);
    int* bsum    = ib + taki((size_t)((totN + SCB - 1) / SCB) + 1);
    ioff = (ioff + 7) & ~(size_t)7;   // 16B-align the bf16 arena

    // ---- bf16 weight arenas ----------------------------------------------
    unsigned short* warena = (unsigned short*)(ib + ioff);
    size_t woff = 0;
    WBatch wb; int nW = 0; long maxWTot = 0;
    auto reg = [&](const float* src, int K, int N, int tr) {
        int Kpad = (K + 31) & ~31;
        unsigned short* dst = warena + woff;
        woff += (size_t)N * Kpad;
        long tot = (long)N * Kpad; if (tot > maxWTot) maxWTot = tot;
        wb.d[nW].src = src; wb.d[nW].dst = dst; wb.d[nW].K = K;
        wb.d[nW].N = N; wb.d[nW].Kpad = Kpad; wb.d[nW].tr = tr;
        ++nW;
        WArena a; a.p = dst; a.Kpad = Kpad; return a;
    };
    WArena wa_emb = reg(W_emb, FV, HD, 1);
    WArena wa_main[2], wa_s2m[2], wa_gm[2], wa_q[2], wa_k[2], wa_mrg[2], wa_gs[2];
    for (int t = 0; t < D && t < 2; ++t) {
        wa_main[t] = reg(gW_main + (size_t)t * HD * HD, HD, HD, 1);
        wa_s2m[t]  = reg(gW_s2m  + (size_t)t * HD * HD, HD, HD, 1);
        wa_gm[t]   = reg(gW_gm   + (size_t)t * 2 * HD * HD, 2 * HD, HD, 1);
        wa_q[t]    = reg(gW_q    + (size_t)t * HD * HD, HD, HD, 1);
        wa_k[t]    = reg(gW_k    + (size_t)t * HD * HD, HD, HD, 1);
        wa_mrg[t]  = reg(gW_mrg  + (size_t)t * HD * HD, HD, HD, 1);
        wa_gs[t]   = reg(gW_gs   + (size_t)t * 2 * HD * HD, 2 * HD, HD, 1);
    }
    WArena wa_mih = reg(gm_Wih, HD, 3 * HD, 0);   // GRU: x@Wih.T -> WT = Wih as-is
    WArena wa_mhh = reg(gm_Whh, HD, 3 * HD, 0);
    WArena wa_sih = reg(gs_Wih, HD, 3 * HD, 0);
    WArena wa_shh = reg(gs_Whh, HD, 3 * HD, 0);
    WArena wa_s0 = reg(W_s0, Fs, HD, 1);
    WArena wa_s1 = reg(W_s1, HD, HD, 1);
    WArena wa_so = reg(W_so, Fs + 2 * HD, HD, 1);
    WArena wa_m0 = reg(W_m0, Fm, HD, 1);
    WArena wa_m1 = reg(W_m1, HD, HD, 1);
    WArena wa_mo = reg(W_mo, Fm + 2 * HD, HD, 1);
    WArena wa_a0 = reg(W_a0, 2 * HD, HD, 1);
    WArena wa_a1 = reg(W_a1, HD, HD, 1);
    WArena wa_ao = reg(W_ao, 4 * HD, HD, 1);
    WArena wa_ds = reg(W_ds, HD, HD, 1);
    WArena wa_dc = reg(W_dc, HD, HD, 1);

    if (ws_size < off * sizeof(float) + ioff * sizeof(int) + woff * sizeof(unsigned short))
        return;

    {
        dim3 g((unsigned)((maxWTot + 255) / 256), nW);
        hipLaunchKernelGGL(convert_weights, g, dim3(256), 0, stream, wb);
    }

    // ---- CSR build --------------------------------------------------------
    hipMemsetAsync(cnt_all, 0, (size_t)totN * sizeof(int), stream);
    for (int g = 0; g < 8; ++g)
        hist_k<<<gupd((size_t)nE[g]), 256, 0, stream>>>(cnt_all + baseN[g], dsts[g], nE[g]);
    const int nScanBlocks = (totN + SCB - 1) / SCB;
    scan_sums<<<nScanBlocks, 256, 0, stream>>>(cnt_all, totN, bsum);
    scan_bsum<<<1, 64, 0, stream>>>(bsum, nScanBlocks);
    scan_write<<<nScanBlocks, 256, 0, stream>>>(cnt_all, totN, bsum, rp_all);
    hipMemcpyAsync(cur_all, rp_all, (size_t)totN * sizeof(int), hipMemcpyDeviceToDevice, stream);
    for (int g = 0; g < 8; ++g)
        fill_k<<<gupd((size_t)nE[g]), 256, 0, stream>>>(ei_all, cur_all + baseN[g], dsts[g], nE[g]);

    const int* rp_v = rp_all + baseN[0];
    const int* rp_c = rp_all + baseN[1];
    const int* rp_s = rp_all + baseN[2];
    const int* rp_m = rp_all + baseN[3];
    const int* rp_p = rp_all + baseN[4];
    const int* rp_q = rp_all + baseN[5];
    const int* rp_a = rp_all + baseN[6];
    const int* rp_b = rp_all + baseN[7];
    const int* ei = ei_all;

    // ---- embedding + super-node init (GWM stays fp32) ---------------------
    gemm1(stream, vert_x, FV, 0, wa_emb, b_emb, vert, Nv, HD, 1, 0);
    seg_gather<<<gup4(B), 256, 0, stream>>>(supe, vert, rp_b, ei, nullptr, nullptr,
                                            nullptr, B, HD, 0, 0, 0, 0, 0);

    // ---- GWM iterations ---------------------------------------------------
    float* Ta = T;            float* Tb = T + NvH;     float* Tc = T + 2 * NvH;
    float* Td = T + 3 * NvH;  float* Te = T + 4 * NvH; float* Tf = T + 7 * NvH;
    for (int t = 0; t < D; ++t) {
        const float* bgm = gb_gm + (size_t)t * HD;
        const float* bgs = gb_gs + (size_t)t * HD;

        gemm1(stream, vert, HD, 0, wa_main[t], nullptr, Ta, Nv, HD, 0, 0);
        seg_gather<<<gup4((size_t)Nv), 256, 0, stream>>>(Tb, Ta, rp_v, ei, vert_src,
                                                         nullptr, nullptr, Nv, HD, 0, 1, 0, 0, 0);
        gemm1(stream, supe, HD, 0, wa_s2m[t], nullptr, tsml, B, HD, 1, 0);
        gather128<<<gupd(NvH), 256, 0, stream>>>(Tc, tsml, vbatch, Nv);
        gemmX(stream, Tb, HD, 0, Tc, HD, 0, nullptr, 0, 0, wa_gm[t], bgm, Td, Nv, HD, 3, 0, Tb, Tc);
        gemm1(stream, Td, HD, 0, wa_mih, gm_bih, Te, Nv, 3 * HD, 0, 0);
        gemm1(stream, vert, HD, 0, wa_mhh, gm_bhh, Tf, Nv, 3 * HD, 0, 0);
        gru_gate<<<gupd(NvH), 256, 0, stream>>>(vert, Te, Tf, Nv);
        gemm1(stream, vert, HD, 0, wa_k[t], nullptr, Ta, Nv, HD, 0, 0);
        gemm1(stream, supe, HD, 0, wa_q[t], nullptr, qsup, B, HD, 0, 0);
        dot_score<<<gupd((size_t)Nv), 256, 0, stream>>>(score, Ta, qsup, vbatch, Nv);
        seg_softmax_csr<<<gup4(B), 256, 0, stream>>>(score, rp_b, ei, B);
        seg_gather<<<gup4(B), 256, 0, stream>>>(pool, vert, rp_b, ei, nullptr, score,
                                                nullptr, B, HD, 0, 0, 1, 0, 0);
        gemm1(stream, pool, HD, 0, wa_mrg[t], nullptr, msup, B, HD, 1, 0);
        gemmX(stream, msup, HD, 0, supe, HD, 0, nullptr, 0, 0, wa_gs[t], bgs, zsup, B, HD, 3, 0, msup, supe);
        gemm1(stream, zsup, HD, 0, wa_sih, gs_bih, gis, B, 3 * HD, 0, 0);
        gemm1(stream, supe, HD, 0, wa_shh, gs_bhh, ghs, B, 3 * HD, 0, 0);
        gru_gate<<<gupd((size_t)B * HD), 256, 0, stream>>>(supe, gis, ghs, B);
    }

    // ---- Group module (out bf16) ------------------------------------------
    seg_gather<<<gup4((size_t)NG), 256, 0, stream>>>(grp_h, vert, rp_c, ei, comp_src,
                                                     nullptr, nullptr, NG, HD, 0, 0, 2, 0, 1);

    // ---- site conv stack (bf16 activations) -------------------------------
    unsigned short* T1h = (unsigned short*)T;
    unsigned short* T2h = (unsigned short*)(T + NsH);
    unsigned short* T3h = (unsigned short*)(T + 2 * NsH);
    gemm1(stream, site_x, Fs, 0, wa_s0, nullptr, T1h, Ns, HD, 0, 1);
    seg_gather<<<gup4((size_t)Ns), 256, 0, stream>>>(T2h, T1h, rp_s, ei, site_src,
                                                     nullptr, b_s0, Ns, HD, 0, 1, 0, 1, 1);
    gemm1(stream, T2h, HD, 1, wa_s1, nullptr, T1h, Ns, HD, 0, 1);
    seg_gather<<<gup4((size_t)Ns), 256, 0, stream>>>(T3h, T1h, rp_s, ei, site_src,
                                                     nullptr, b_s1, Ns, HD, 0, 1, 0, 1, 1);
    gemmX(stream, site_x, Fs, 0, T2h, HD, 1, T3h, HD, 1, wa_so, b_so, site_o_h, Ns, HD, 1, 1);

    // ---- masf conv stack ---------------------------------------------------
    gemm1(stream, masf_x, Fm, 0, wa_m0, nullptr, T1h, Nm, HD, 0, 1);
    seg_gather<<<gup4((size_t)Nm), 256, 0, stream>>>(T2h, T1h, rp_m, ei, masf_src,
                                                     nullptr, b_m0, Nm, HD, 0, 1, 0, 1, 1);
    gemm1(stream, T2h, HD, 1, wa_m1, nullptr, T1h, Nm, HD, 0, 1);
    seg_gather<<<gup4((size_t)Nm), 256, 0, stream>>>(T3h, T1h, rp_m, ei, masf_src,
                                                     nullptr, b_m1, Nm, HD, 0, 1, 0, 1, 1);
    gemmX(stream, masf_x, Fm, 0, T2h, HD, 1, T3h, HD, 1, wa_mo, b_mo, masf_o_h, Nm, HD, 1, 1);

    // ---- anchor pooling (bf16 in/out) -------------------------------------
    seg_gather<<<gup4((size_t)NA), 256, 0, stream>>>(anch_h, site_o_h, rp_p, ei, prot_src,
                                                     prot_ea, nullptr, NA, 2 * HD, 0, 0, 3, 1, 1);
    seg_gather<<<gup4((size_t)NA), 256, 0, stream>>>(anch_h, masf_o_h, rp_q, ei, prom_src,
                                                     prom_ea, nullptr, NA, 2 * HD, HD, 0, 3, 1, 1);

    // ---- anchor conv stack -------------------------------------------------
    gemm1(stream, anch_h, 2 * HD, 1, wa_a0, nullptr, axw_h, NA, HD, 0, 1);
    seg_gather<<<gup4((size_t)NA), 256, 0, stream>>>(ah1_h, axw_h, rp_a, ei, anch_src,
                                                     nullptr, b_a0, NA, HD, 0, 1, 0, 1, 1);
    gemm1(stream, ah1_h, HD, 1, wa_a1, nullptr, axw_h, NA, HD, 0, 1);
    seg_gather<<<gup4((size_t)NA), 256, 0, stream>>>(ah2_h, axw_h, rp_a, ei, anch_src,
                                                     nullptr, b_a1, NA, HD, 0, 1, 0, 1, 1);
    gemmX(stream, anch_h, 2 * HD, 1, ah1_h, HD, 1, ah2_h, HD, 1, wa_ao, b_ao, aout_h, NA, HD, 1, 1);

    // ---- distance heads (fp32 outputs for pdist) ---------------------------
    gemm1(stream, aout_h, HD, 1, wa_ds, b_ds, pa, NA, HD, 1, 0);
    gemm1(stream, grp_h, HD, 1, wa_dc, b_dc, pg, NG, HD, 1, 0);
    float* outp = (float*)d_out;
    pdist_k<<<gupd((size_t)Pag), 256, 0, stream>>>(outp, pa, pg, ag_a, ag_g, Pag);
    pdist_k<<<gupd((size_t)Paa), 256, 0, stream>>>(outp + Pag, pa, pa, aa0, aa1, Paa);
    pdist_k<<<gupd((size_t)Pgg), 256, 0, stream>>>(outp + Pag + Paa, pg, pg, gg0, gg1, Pgg);
}

// Round 11
// 1383.243 us; speedup vs baseline: 1.0199x; 1.0199x over previous
//
#include <hip/hip_runtime.h>
#include <math.h>

#define HD 128  // hidden dim

typedef __bf16 bf16x8 __attribute__((ext_vector_type(8)));
typedef unsigned short u16x8 __attribute__((ext_vector_type(8)));
typedef float f32x4 __attribute__((ext_vector_type(4)));

__device__ __forceinline__ unsigned short f2bf(float f) {
    unsigned u = __float_as_uint(f);
    unsigned r = u + 0x7FFFu + ((u >> 16) & 1u);   // RTN-even
    return (unsigned short)(r >> 16);
}

// ---------------------------------------------------------------- weight convert
#define MAXW 32
struct WDesc { const float* src; unsigned short* dst; int K, N, Kpad, tr; };
struct WBatch { WDesc d[MAXW]; };

__global__ void convert_weights(WBatch wb)
{
    WDesc d = wb.d[blockIdx.y];
    long total = (long)d.N * d.Kpad;
    long i = (long)blockIdx.x * 256 + threadIdx.x;
    if (i >= total) return;
    int n = (int)(i / d.Kpad), k = (int)(i % d.Kpad);
    float v = 0.f;
    if (k < d.K) v = d.tr ? d.src[(size_t)k * d.N + n] : d.src[(size_t)n * d.K + k];
    d.dst[i] = f2bf(v);
}

// ---------------------------------------------------------------- MFMA GEMM
// C[M,N] = act( [A0|A1|A2] @ W + bias ), W as bf16 WT[N][Kpad].
// act: 0 none, 1 lrelu, 2 sigmoid, 3 gate: C = z*G1 + (1-z)*G2, z=sigmoid(v).
// 256 thr = 4 waves; tile 64x128; DEPTH-2 register pipeline: prologue loads
// tiles 0..2, loop issues tile kt+3 -> ~2 iterations in flight (covers L2
// latency); one raw s_barrier/tile, only lgkmcnt drained.
// C/D: col=lane&15, row=(lane>>4)*4+reg  [m89-verified].
__global__ __launch_bounds__(256)
void gemm_mfma(const float* __restrict__ A0, const float* __restrict__ A1,
               const float* __restrict__ A2, int K0, int K1, int K2,
               int lda0, int lda1, int lda2,
               const unsigned short* __restrict__ WT, int Kpad,
               const float* __restrict__ bias, float* __restrict__ C,
               int M, int N, int act,
               const float* __restrict__ G1, const float* __restrict__ G2)
{
    __shared__ __align__(16) unsigned short sA[2][64][40];
    __shared__ __align__(16) unsigned short sW[2][128][40];

    const int tid = threadIdx.x;
    const int lane = tid & 63, w = tid >> 6;
    const int mBase = blockIdx.x * 64;
    const int nBase = blockIdx.y * 128;
    const int Ktot = K0 + K1 + K2;
    const int colb = w * 32;
    const int c16 = lane & 15, g = lane >> 4;

    f32x4 acc[4][2];
#pragma unroll
    for (int i = 0; i < 4; ++i)
#pragma unroll
        for (int j = 0; j < 2; ++j) acc[i][j] = (f32x4){0.f, 0.f, 0.f, 0.f};

    const int kTiles = (Ktot + 31) / 32;

    auto loadTile = [&](int kt, float f[8], u16x8& h0, u16x8& h1) {
        const int k0g = kt * 32;
        const float* Ab; int lda, kloc, segK;
        if (k0g < K0)           { Ab = A0; lda = lda0; kloc = k0g;           segK = K0; }
        else if (k0g < K0 + K1) { Ab = A1; lda = lda1; kloc = k0g - K0;      segK = K1; }
        else                    { Ab = A2; lda = lda2; kloc = k0g - K0 - K1; segK = K2; }
        int row = tid >> 2, kq = (tid & 3) * 8;
        int gr = mBase + row;
        if (gr < M && ((lda & 3) == 0) && (kloc + kq + 8 <= segK)) {
            const float* ap = Ab + (size_t)gr * lda + kloc + kq;
            float4 v0 = *(const float4*)ap, v1 = *(const float4*)(ap + 4);
            f[0] = v0.x; f[1] = v0.y; f[2] = v0.z; f[3] = v0.w;
            f[4] = v1.x; f[5] = v1.y; f[6] = v1.z; f[7] = v1.w;
        } else {
#pragma unroll
            for (int i = 0; i < 8; ++i) {
                int kk = kloc + kq + i;
                f[i] = (gr < M && kk < segK) ? Ab[(size_t)gr * lda + kk] : 0.f;
            }
        }
        int col = tid >> 1, kh = (tid & 1) * 16;
        const unsigned short* wp = WT + (size_t)(nBase + col) * Kpad + k0g + kh;
        h0 = *(const u16x8*)wp;
        h1 = *(const u16x8*)(wp + 8);
    };
    auto stageWrite = [&](int buf, const float f[8], u16x8 h0, u16x8 h1) {
        int row = tid >> 2, kq = (tid & 3) * 8;
        u16x8 h;
#pragma unroll
        for (int i = 0; i < 8; ++i) h[i] = f2bf(f[i]);
        *(u16x8*)&sA[buf][row][kq] = h;
        int col = tid >> 1, kh = (tid & 1) * 16;
        *(u16x8*)&sW[buf][col][kh] = h0;
        *(u16x8*)&sW[buf][col][kh + 8] = h1;
    };
    auto compute = [&](int buf) {
        bf16x8 bfr0 = __builtin_bit_cast(bf16x8, *(const u16x8*)&sW[buf][colb + c16][g * 8]);
        bf16x8 bfr1 = __builtin_bit_cast(bf16x8, *(const u16x8*)&sW[buf][colb + 16 + c16][g * 8]);
#pragma unroll
        for (int rf = 0; rf < 4; ++rf) {
            bf16x8 af = __builtin_bit_cast(bf16x8, *(const u16x8*)&sA[buf][rf * 16 + c16][g * 8]);
            acc[rf][0] = __builtin_amdgcn_mfma_f32_16x16x32_bf16(af, bfr0, acc[rf][0], 0, 0, 0);
            acc[rf][1] = __builtin_amdgcn_mfma_f32_16x16x32_bf16(af, bfr1, acc[rf][1], 0, 0, 0);
        }
    };

    // prologue: stage tile 0, prefetch tiles 1 and 2 into registers
    float f1[8], f2[8]; u16x8 w1a, w1b, w2a, w2b;
    {
        float f0[8]; u16x8 w0a, w0b;
        loadTile(0, f0, w0a, w0b);
        stageWrite(0, f0, w0a, w0b);
        if (kTiles > 1) loadTile(1, f1, w1a, w1b);
        if (kTiles > 2) loadTile(2, f2, w2a, w2b);
    }
    asm volatile("s_waitcnt lgkmcnt(0)" ::: "memory");
    __builtin_amdgcn_s_barrier();

    int cur = 0;
#pragma unroll 2
    for (int kt = 0; kt < kTiles; ++kt) {
        float fP[8]; u16x8 wPa, wPb;
        const bool pf = (kt + 3 < kTiles);
        if (pf) loadTile(kt + 3, fP, wPa, wPb);     // 2 iterations in flight
        compute(cur);
        if (kt + 1 < kTiles) stageWrite(cur ^ 1, f1, w1a, w1b);
        asm volatile("s_waitcnt lgkmcnt(0)" ::: "memory");
        __builtin_amdgcn_s_barrier();
        if (kt + 2 < kTiles) {
#pragma unroll
            for (int i = 0; i < 8; ++i) f1[i] = f2[i];
            w1a = w2a; w1b = w2b;
        }
        if (pf) {
#pragma unroll
            for (int i = 0; i < 8; ++i) f2[i] = fP[i];
            w2a = wPa; w2b = wPb;
        }
        cur ^= 1;
    }

    // ---- epilogue
#pragma unroll
    for (int cf = 0; cf < 2; ++cf) {
        int col = nBase + colb + cf * 16 + c16;
        float bb = bias ? bias[col] : 0.f;
#pragma unroll
        for (int rf = 0; rf < 4; ++rf) {
            int r0 = mBase + rf * 16 + g * 4;
#pragma unroll
            for (int r = 0; r < 4; ++r) {
                int gr = r0 + r;
                if (gr >= M) continue;
                size_t o = (size_t)gr * N + col;
                float v = acc[rf][cf][r] + bb;
                if (act == 1) v = v > 0.f ? v : 0.1f * v;
                else if (act == 2) v = 1.f / (1.f + expf(-v));
                else if (act == 3) {
                    float z = 1.f / (1.f + expf(-v));
                    v = z * G1[o] + (1.f - z) * G2[o];
                }
                C[o] = v;
            }
        }
    }
}

// ---------------------------------------------------------------- CSR build
__global__ void hist_k(int* __restrict__ cnt, const int* __restrict__ dst, int E)
{
    int i = blockIdx.x * 256 + threadIdx.x;
    if (i < E) atomicAdd(&cnt[dst[i]], 1);
}

#define SCB 4096

__global__ __launch_bounds__(256)
void scan_sums(const int* __restrict__ cnt, int n, int* __restrict__ bsum)
{
    __shared__ int red[256];
    int t = threadIdx.x;
    int base = blockIdx.x * SCB + t * 16;
    int s = 0;
#pragma unroll
    for (int i = 0; i < 16; ++i) { int idx = base + i; if (idx < n) s += cnt[idx]; }
    red[t] = s; __syncthreads();
    for (int st = 128; st > 0; st >>= 1) {
        if (t < st) red[t] += red[t + st];
        __syncthreads();
    }
    if (t == 0) bsum[blockIdx.x] = red[0];
}

__global__ void scan_bsum(int* __restrict__ bsum, int nb)
{
    if (threadIdx.x == 0) {
        int run = 0;
        for (int i = 0; i < nb; ++i) { int v = bsum[i]; bsum[i] = run; run += v; }
    }
}

__global__ __launch_bounds__(256)
void scan_write(const int* __restrict__ cnt, int n, const int* __restrict__ bsum,
                int* __restrict__ rp)
{
    __shared__ int a0[256], a1[256];
    int t = threadIdx.x;
    int base = blockIdx.x * SCB + t * 16;
    int v[16]; int s = 0;
#pragma unroll
    for (int i = 0; i < 16; ++i) { int idx = base + i; v[i] = (idx < n) ? cnt[idx] : 0; s += v[i]; }
    a0[t] = s; __syncthreads();
    int* cur = a0; int* nxt = a1;
    for (int st = 1; st < 256; st <<= 1) {
        int val = cur[t] + ((t >= st) ? cur[t - st] : 0);
        nxt[t] = val; __syncthreads();
        int* tmp = cur; cur = nxt; nxt = tmp;
    }
    int run = bsum[blockIdx.x] + (t > 0 ? cur[t - 1] : 0);
#pragma unroll
    for (int i = 0; i < 16; ++i) {
        int idx = base + i;
        if (idx < n) {
            rp[idx] = run; run += v[i];
            if (idx == n - 1) rp[n] = run;
        }
    }
}

__global__ void fill_k(int* __restrict__ eidx, int* __restrict__ cursor,
                       const int* __restrict__ dst, int E)
{
    int i = blockIdx.x * 256 + threadIdx.x;
    if (i < E) eidx[atomicAdd(&cursor[dst[i]], 1)] = i;
}

// ---------------------------------------------------------------- CSR gather
// One wave per destination row; lane covers 2 feats (float2).
// mode 0: w=1   1: w=wattr[e]   2: w=1/deg   3: w=softmax(6-wattr)[e]
__global__ __launch_bounds__(256)
void seg_gather(float* __restrict__ out, const float* __restrict__ X,
                const int* __restrict__ rowptr, const int* __restrict__ eidx,
                const int* __restrict__ src, const float* __restrict__ wattr,
                const float* __restrict__ bias, int n, int ostride, int ooff,
                int act, int mode)
{
    int d = blockIdx.x * 4 + (threadIdx.x >> 6);
    if (d >= n) return;
    int lane = threadIdx.x & 63;
    int lo = rowptr[d], hi = rowptr[d + 1];
    float w0 = 1.f, mx = 0.f, iden = 0.f;
    if (mode == 2) w0 = (hi > lo) ? 1.f / (float)(hi - lo) : 0.f;
    if (mode == 3) {
        float mxl = -1e30f;
        for (int base = lo; base < hi; base += 64) {
            int i = base + lane;
            if (i < hi) mxl = fmaxf(mxl, 6.f - wattr[eidx[i]]);
        }
#pragma unroll
        for (int o = 32; o; o >>= 1) mxl = fmaxf(mxl, __shfl_xor(mxl, o));
        mx = mxl;
        float dl = 0.f;
        for (int base = lo; base < hi; base += 64) {
            int i = base + lane;
            if (i < hi) dl += expf(6.f - wattr[eidx[i]] - mx);
        }
#pragma unroll
        for (int o = 32; o; o >>= 1) dl += __shfl_xor(dl, o);
        iden = 1.f / dl;
    }

    float ax = 0.f, ay = 0.f;
    int i = lo;
    for (; i + 4 <= hi; i += 4) {
        int e0 = eidx[i], e1 = eidx[i + 1], e2 = eidx[i + 2], e3 = eidx[i + 3];
        int s0 = src ? src[e0] : e0, s1 = src ? src[e1] : e1;
        int s2 = src ? src[e2] : e2, s3 = src ? src[e3] : e3;
        float w0v, w1v, w2v, w3v;
        if (mode == 0) { w0v = w1v = w2v = w3v = 1.f; }
        else if (mode == 1) { w0v = wattr[e0]; w1v = wattr[e1]; w2v = wattr[e2]; w3v = wattr[e3]; }
        else if (mode == 2) { w0v = w1v = w2v = w3v = w0; }
        else {
            w0v = expf(6.f - wattr[e0] - mx) * iden;
            w1v = expf(6.f - wattr[e1] - mx) * iden;
            w2v = expf(6.f - wattr[e2] - mx) * iden;
            w3v = expf(6.f - wattr[e3] - mx) * iden;
        }
        float2 v0 = *(const float2*)(X + (size_t)s0 * HD + 2 * lane);
        float2 v1 = *(const float2*)(X + (size_t)s1 * HD + 2 * lane);
        float2 v2 = *(const float2*)(X + (size_t)s2 * HD + 2 * lane);
        float2 v3 = *(const float2*)(X + (size_t)s3 * HD + 2 * lane);
        ax += w0v * v0.x + w1v * v1.x + w2v * v2.x + w3v * v3.x;
        ay += w0v * v0.y + w1v * v1.y + w2v * v2.y + w3v * v3.y;
    }
    for (; i < hi; ++i) {
        int e = eidx[i];
        int s = src ? src[e] : e;
        float w;
        if (mode == 0) w = 1.f;
        else if (mode == 1) w = wattr[e];
        else if (mode == 2) w = w0;
        else w = expf(6.f - wattr[e] - mx) * iden;
        float2 v = *(const float2*)(X + (size_t)s * HD + 2 * lane);
        ax += w * v.x; ay += w * v.y;
    }
    if (bias) { float2 b = *(const float2*)(bias + 2 * lane); ax += b.x; ay += b.y; }
    if (act == 1) { ax = ax > 0.f ? ax : 0.1f * ax; ay = ay > 0.f ? ay : 0.1f * ay; }
    *(float2*)(out + (size_t)d * ostride + ooff + 2 * lane) = make_float2(ax, ay);
}

// ---------------------------------------------------------------- fused segment softmax
__global__ __launch_bounds__(256)
void seg_softmax_csr(float* __restrict__ sc, const int* __restrict__ rowptr,
                     const int* __restrict__ eidx, int n)
{
    int d = blockIdx.x * 4 + (threadIdx.x >> 6);
    if (d >= n) return;
    int lane = threadIdx.x & 63;
    int lo = rowptr[d], hi = rowptr[d + 1];
    float mxl = -1e30f;
    for (int i = lo + lane; i < hi; i += 64) mxl = fmaxf(mxl, sc[eidx[i]]);
#pragma unroll
    for (int o = 32; o; o >>= 1) mxl = fmaxf(mxl, __shfl_xor(mxl, o));
    float dl = 0.f;
    for (int i = lo + lane; i < hi; i += 64) dl += expf(sc[eidx[i]] - mxl);
#pragma unroll
    for (int o = 32; o; o >>= 1) dl += __shfl_xor(dl, o);
    float iden = 1.f / dl;
    for (int i = lo + lane; i < hi; i += 64) {
        int v = eidx[i];
        sc[v] = expf(sc[v] - mxl) * iden;
    }
}

// ---------------------------------------------------------------- misc kernels
__global__ void gather128(float* __restrict__ out, const float* __restrict__ in,
                          const int* __restrict__ idx, int n)
{
    long i = (long)blockIdx.x * 256 + threadIdx.x;
    if (i >= (long)n * HD) return;
    int r = (int)(i >> 7), f = (int)(i & 127);
    out[i] = in[(size_t)idx[r] * HD + f];
}

__global__ void gru_gate(float* __restrict__ h, const float* __restrict__ gi,
                         const float* __restrict__ gh, int M)
{
    long i = (long)blockIdx.x * 256 + threadIdx.x;
    if (i >= (long)M * HD) return;
    int row = (int)(i >> 7), f = (int)(i & 127);
    size_t o = (size_t)row * 384 + f;
    float r = 1.f / (1.f + expf(-(gi[o] + gh[o])));
    float z = 1.f / (1.f + expf(-(gi[o + 128] + gh[o + 128])));
    float n = tanhf(gi[o + 256] + r * gh[o + 256]);
    h[i] = (1.f - z) * n + z * h[i];
}

// score[v] = dot(vert[v], u[batch[v]]) / sqrt(128)   (u = q @ Wk^T)
__global__ void dot_score(float* __restrict__ sc, const float* __restrict__ vert,
                          const float* __restrict__ u, const int* __restrict__ batch, int n)
{
    int v = blockIdx.x * 256 + threadIdx.x;
    if (v >= n) return;
    const float4* a = (const float4*)(vert + (size_t)v * HD);
    const float4* q = (const float4*)(u + (size_t)batch[v] * HD);
    float acc = 0.f;
#pragma unroll
    for (int i = 0; i < 32; ++i) {
        float4 x = a[i], y = q[i];
        acc += x.x * y.x + x.y * y.y + x.z * y.z + x.w * y.w;
    }
    sc[v] = acc * 0.08838834764831843f;  // 1/sqrt(128)
}

__global__ void pdist_k(float* __restrict__ out, const float* __restrict__ A,
                        const float* __restrict__ Bm, const int* __restrict__ ia,
                        const int* __restrict__ ib, int P)
{
    int p = blockIdx.x * 256 + threadIdx.x;
    if (p >= P) return;
    const float4* a = (const float4*)(A + (size_t)ia[p] * HD);
    const float4* b = (const float4*)(Bm + (size_t)ib[p] * HD);
    float acc = 0.f;
#pragma unroll
    for (int i = 0; i < 32; ++i) {
        float4 x = a[i], y = b[i];
        float d0 = x.x - y.x + 1e-6f, d1 = x.y - y.y + 1e-6f;
        float d2 = x.z - y.z + 1e-6f, d3 = x.w - y.w + 1e-6f;
        acc += d0 * d0 + d1 * d1 + d2 * d2 + d3 * d3;
    }
    out[p] = sqrtf(acc);
}

// ---------------------------------------------------------------- host

static inline unsigned gupd(size_t n) { return (unsigned)((n + 255) / 256); }
static inline unsigned gup4(size_t n) { return (unsigned)((n + 3) / 4); }

struct WArena { unsigned short* p; int Kpad; };

static void gemm3s(hipStream_t st, const float* A0, int K0, const float* A1, int K1,
                   const float* A2, int K2, WArena wa, const float* bias,
                   float* C, int M, int N, int act,
                   const float* G1 = nullptr, const float* G2 = nullptr)
{
    dim3 g((M + 63) / 64, N / 128);
    hipLaunchKernelGGL(gemm_mfma, g, dim3(256), 0, st, A0, A1, A2, K0, K1, K2,
                       K0, K1, K2, wa.p, wa.Kpad, bias, C, M, N, act, G1, G2);
}
static void gemm1(hipStream_t st, const float* A, int K, WArena wa, const float* bias,
                  float* C, int M, int N, int act)
{ gemm3s(st, A, K, nullptr, 0, nullptr, 0, wa, bias, C, M, N, act); }
static void gemm2g(hipStream_t st, const float* A0, int K0, const float* A1, int K1,
                   WArena wa, const float* bias, float* C, int M, int N, int act,
                   const float* G1 = nullptr, const float* G2 = nullptr)
{ gemm3s(st, A0, K0, A1, K1, nullptr, 0, wa, bias, C, M, N, act, G1, G2); }

extern "C" void kernel_launch(void* const* d_in, const int* in_sizes, int n_in,
                              void* d_out, int out_size, void* d_ws, size_t ws_size,
                              hipStream_t stream)
{
    (void)n_in; (void)out_size;
    const float* vert_x  = (const float*)d_in[0];
    const float* site_x  = (const float*)d_in[1];
    const float* masf_x  = (const float*)d_in[2];
    const float* prot_ea = (const float*)d_in[3];
    const float* prom_ea = (const float*)d_in[4];
    const int* vert_src = (const int*)d_in[5];
    const int* vert_dst = (const int*)d_in[6];
    const int* vbatch   = (const int*)d_in[7];
    const int* comp_src = (const int*)d_in[8];
    const int* comp_dst = (const int*)d_in[9];
    const int* site_src = (const int*)d_in[10];
    const int* site_dst = (const int*)d_in[11];
    const int* masf_src = (const int*)d_in[12];
    const int* masf_dst = (const int*)d_in[13];
    const int* prot_src = (const int*)d_in[14];
    const int* prot_dst = (const int*)d_in[15];
    const int* prom_src = (const int*)d_in[16];
    const int* prom_dst = (const int*)d_in[17];
    const int* anch_src = (const int*)d_in[18];
    const int* anch_dst = (const int*)d_in[19];
    const int* ag_a = (const int*)d_in[20];
    const int* ag_g = (const int*)d_in[21];
    const int* aa0  = (const int*)d_in[22];
    const int* aa1  = (const int*)d_in[23];
    const int* gg0  = (const int*)d_in[24];
    const int* gg1  = (const int*)d_in[25];
    const float* W_emb = (const float*)d_in[26];
    const float* b_emb = (const float*)d_in[27];
    const float* gW_main = (const float*)d_in[28];
    const float* gW_s2m  = (const float*)d_in[29];
    const float* gW_gm   = (const float*)d_in[30];
    const float* gb_gm   = (const float*)d_in[31];
    const float* gW_q    = (const float*)d_in[32];
    const float* gW_k    = (const float*)d_in[33];
    const float* gW_mrg  = (const float*)d_in[34];
    const float* gW_gs   = (const float*)d_in[35];
    const float* gb_gs   = (const float*)d_in[36];
    const float* gm_Wih = (const float*)d_in[37];
    const float* gm_Whh = (const float*)d_in[38];
    const float* gm_bih = (const float*)d_in[39];
    const float* gm_bhh = (const float*)d_in[40];
    const float* gs_Wih = (const float*)d_in[41];
    const float* gs_Whh = (const float*)d_in[42];
    const float* gs_bih = (const float*)d_in[43];
    const float* gs_bhh = (const float*)d_in[44];
    const float* W_s0 = (const float*)d_in[45];
    const float* b_s0 = (const float*)d_in[46];
    const float* W_s1 = (const float*)d_in[47];
    const float* b_s1 = (const float*)d_in[48];
    const float* W_so = (const float*)d_in[49];
    const float* b_so = (const float*)d_in[50];
    const float* W_m0 = (const float*)d_in[51];
    const float* b_m0 = (const float*)d_in[52];
    const float* W_m1 = (const float*)d_in[53];
    const float* b_m1 = (const float*)d_in[54];
    const float* W_mo = (const float*)d_in[55];
    const float* b_mo = (const float*)d_in[56];
    const float* W_a0 = (const float*)d_in[57];
    const float* b_a0 = (const float*)d_in[58];
    const float* W_a1 = (const float*)d_in[59];
    const float* b_a1 = (const float*)d_in[60];
    const float* W_ao = (const float*)d_in[61];
    const float* b_ao = (const float*)d_in[62];
    const float* W_ds = (const float*)d_in[63];
    const float* b_ds = (const float*)d_in[64];
    const float* W_dc = (const float*)d_in[65];
    const float* b_dc = (const float*)d_in[66];

    const int B = 256, NG = 4000, NA = 10000, Ns = 80000, Nm = 80000;
    const int Nv = in_sizes[7];
    const int FV = in_sizes[0] / Nv;
    const int Fs = in_sizes[1] / Ns;
    const int Fm = in_sizes[2] / Nm;
    const int Ev = in_sizes[5], Ec = in_sizes[8], Es = in_sizes[10], Em = in_sizes[12];
    const int Ep = in_sizes[14], Ea = in_sizes[18];
    const int Pag = in_sizes[20], Paa = in_sizes[22], Pgg = in_sizes[24];
    const int D = in_sizes[28] / (HD * HD);

    // ---- workspace layout (floats) --------------------------------------
    float* ws = (float*)d_ws;
    size_t off = 0;
    auto take = [&](size_t n) { size_t o = off; off += n; return o; };
    float* vert  = ws + take((size_t)Nv * HD);
    float* supe  = ws + take((size_t)B * HD);
    float* qsup  = ws + take((size_t)B * HD);
    float* usup  = ws + take((size_t)B * HD);
    float* pool  = ws + take((size_t)B * HD);
    float* msup  = ws + take((size_t)B * HD);
    float* zsup  = ws + take((size_t)B * HD);
    float* gis   = ws + take((size_t)B * 3 * HD);
    float* ghs   = ws + take((size_t)B * 3 * HD);
    float* tsml  = ws + take((size_t)B * HD);
    float* grp   = ws + take((size_t)NG * HD);
    float* site_o = ws + take((size_t)Ns * HD);
    float* masf_o = ws + take((size_t)Nm * HD);
    float* anch  = ws + take((size_t)NA * 2 * HD);
    float* ah1   = ws + take((size_t)NA * HD);
    float* ah2   = ws + take((size_t)NA * HD);
    float* axw   = ws + take((size_t)NA * HD);
    float* aout  = ws + take((size_t)NA * HD);
    float* pa    = ws + take((size_t)NA * HD);
    float* pg    = ws + take((size_t)NG * HD);
    float* score = ws + take((size_t)Nv);
    const size_t NvH = (size_t)Nv * HD, NsH = (size_t)Ns * HD;
    float* T = ws + take(3 * NsH);   // shared temp region

    // ---- CSR arrays (ints), concatenated layout --------------------------
    const int nN[8] = {Nv, NG, Ns, Nm, NA, NA, NA, B};
    const int nE[8] = {Ev, Ec, Es, Em, Ep, Ep, Ea, Nv};
    const int* dsts[8] = {vert_dst, comp_dst, site_dst, masf_dst,
                          prot_dst, prom_dst, anch_dst, vbatch};
    int baseN[9], baseE[9];
    baseN[0] = 0; baseE[0] = 0;
    for (int g = 0; g < 8; ++g) { baseN[g + 1] = baseN[g] + nN[g]; baseE[g + 1] = baseE[g] + nE[g]; }
    const int totN = baseN[8], totE = baseE[8];

    int* ib = (int*)(ws + off);
    size_t ioff = 0;
    auto taki = [&](size_t n) { size_t o = ioff; ioff += n; return o; };
    int* cnt_all = ib + taki((size_t)totN);
    int* rp_all  = ib + taki((size_t)totN + 1);
    int* cur_all = ib + taki((size_t)totN);
    int* ei_all  = ib + taki((size_t)totE);
    int* bsum    = ib + taki((size_t)((totN + SCB - 1) / SCB) + 1);
    ioff = (ioff + 7) & ~(size_t)7;   // 16B-align the bf16 arena

    // ---- bf16 weight arenas ----------------------------------------------
    unsigned short* warena = (unsigned short*)(ib + ioff);
    size_t woff = 0;
    WBatch wb; int nW = 0; long maxWTot = 0;
    auto reg = [&](const float* src, int K, int N, int tr) {
        int Kpad = (K + 31) & ~31;
        unsigned short* dst = warena + woff;
        woff += (size_t)N * Kpad;
        long tot = (long)N * Kpad; if (tot > maxWTot) maxWTot = tot;
        wb.d[nW].src = src; wb.d[nW].dst = dst; wb.d[nW].K = K;
        wb.d[nW].N = N; wb.d[nW].Kpad = Kpad; wb.d[nW].tr = tr;
        ++nW;
        WArena a; a.p = dst; a.Kpad = Kpad; return a;
    };
    WArena wa_emb = reg(W_emb, FV, HD, 1);
    WArena wa_main[2], wa_s2m[2], wa_gm[2], wa_q[2], wa_kT[2], wa_mrg[2], wa_gs[2];
    for (int t = 0; t < D && t < 2; ++t) {
        wa_main[t] = reg(gW_main + (size_t)t * HD * HD, HD, HD, 1);
        wa_s2m[t]  = reg(gW_s2m  + (size_t)t * HD * HD, HD, HD, 1);
        wa_gm[t]   = reg(gW_gm   + (size_t)t * 2 * HD * HD, 2 * HD, HD, 1);
        wa_q[t]    = reg(gW_q    + (size_t)t * HD * HD, HD, HD, 1);
        wa_kT[t]   = reg(gW_k    + (size_t)t * HD * HD, HD, HD, 0);  // u = q @ Wk^T
        wa_mrg[t]  = reg(gW_mrg  + (size_t)t * HD * HD, HD, HD, 1);
        wa_gs[t]   = reg(gW_gs   + (size_t)t * 2 * HD * HD, 2 * HD, HD, 1);
    }
    WArena wa_mih = reg(gm_Wih, HD, 3 * HD, 0);   // GRU: x@Wih.T -> WT = Wih as-is
    WArena wa_mhh = reg(gm_Whh, HD, 3 * HD, 0);
    WArena wa_sih = reg(gs_Wih, HD, 3 * HD, 0);
    WArena wa_shh = reg(gs_Whh, HD, 3 * HD, 0);
    WArena wa_s0 = reg(W_s0, Fs, HD, 1);
    WArena wa_s1 = reg(W_s1, HD, HD, 1);
    WArena wa_so = reg(W_so, Fs + 2 * HD, HD, 1);
    WArena wa_m0 = reg(W_m0, Fm, HD, 1);
    WArena wa_m1 = reg(W_m1, HD, HD, 1);
    WArena wa_mo = reg(W_mo, Fm + 2 * HD, HD, 1);
    WArena wa_a0 = reg(W_a0, 2 * HD, HD, 1);
    WArena wa_a1 = reg(W_a1, HD, HD, 1);
    WArena wa_ao = reg(W_ao, 4 * HD, HD, 1);
    WArena wa_ds = reg(W_ds, HD, HD, 1);
    WArena wa_dc = reg(W_dc, HD, HD, 1);

    if (ws_size < off * sizeof(float) + ioff * sizeof(int) + woff * sizeof(unsigned short))
        return;

    {
        dim3 g((unsigned)((maxWTot + 255) / 256), nW);
        hipLaunchKernelGGL(convert_weights, g, dim3(256), 0, stream, wb);
    }

    // ---- CSR build --------------------------------------------------------
    hipMemsetAsync(cnt_all, 0, (size_t)totN * sizeof(int), stream);
    for (int g = 0; g < 8; ++g)
        hist_k<<<gupd((size_t)nE[g]), 256, 0, stream>>>(cnt_all + baseN[g], dsts[g], nE[g]);
    const int nScanBlocks = (totN + SCB - 1) / SCB;
    scan_sums<<<nScanBlocks, 256, 0, stream>>>(cnt_all, totN, bsum);
    scan_bsum<<<1, 64, 0, stream>>>(bsum, nScanBlocks);
    scan_write<<<nScanBlocks, 256, 0, stream>>>(cnt_all, totN, bsum, rp_all);
    hipMemcpyAsync(cur_all, rp_all, (size_t)totN * sizeof(int), hipMemcpyDeviceToDevice, stream);
    for (int g = 0; g < 8; ++g)
        fill_k<<<gupd((size_t)nE[g]), 256, 0, stream>>>(ei_all, cur_all + baseN[g], dsts[g], nE[g]);

    const int* rp_v = rp_all + baseN[0];
    const int* rp_c = rp_all + baseN[1];
    const int* rp_s = rp_all + baseN[2];
    const int* rp_m = rp_all + baseN[3];
    const int* rp_p = rp_all + baseN[4];
    const int* rp_q = rp_all + baseN[5];
    const int* rp_a = rp_all + baseN[6];
    const int* rp_b = rp_all + baseN[7];
    const int* ei = ei_all;

    // ---- embedding + super-node init ------------------------------------
    gemm1(stream, vert_x, FV, wa_emb, b_emb, vert, Nv, HD, 1);
    seg_gather<<<gup4(B), 256, 0, stream>>>(supe, vert, rp_b, ei, nullptr, nullptr,
                                            nullptr, B, HD, 0, 0, 0);

    // ---- GWM iterations ---------------------------------------------------
    float* Ta = T;            float* Tb = T + NvH;     float* Tc = T + 2 * NvH;
    float* Td = T + 3 * NvH;  float* Te = T + 4 * NvH; float* Tf = T + 7 * NvH;
    for (int t = 0; t < D; ++t) {
        const float* bgm = gb_gm + (size_t)t * HD;
        const float* bgs = gb_gs + (size_t)t * HD;

        gemm1(stream, vert, HD, wa_main[t], nullptr, Ta, Nv, HD, 0);
        seg_gather<<<gup4((size_t)Nv), 256, 0, stream>>>(Tb, Ta, rp_v, ei, vert_src,
                                                         nullptr, nullptr, Nv, HD, 0, 1, 0);
        gemm1(stream, supe, HD, wa_s2m[t], nullptr, tsml, B, HD, 1);
        gather128<<<gupd(NvH), 256, 0, stream>>>(Tc, tsml, vbatch, Nv);
        gemm2g(stream, Tb, HD, Tc, HD, wa_gm[t], bgm, Td, Nv, HD, 3, Tb, Tc);
        gemm1(stream, Td, HD, wa_mih, gm_bih, Te, Nv, 3 * HD, 0);
        gemm1(stream, vert, HD, wa_mhh, gm_bhh, Tf, Nv, 3 * HD, 0);
        gru_gate<<<gupd(NvH), 256, 0, stream>>>(vert, Te, Tf, Nv);
        // attention: u_b = (supe@Wq) @ Wk^T  (tiny), score = vert . u[batch]
        gemm1(stream, supe, HD, wa_q[t], nullptr, qsup, B, HD, 0);
        gemm1(stream, qsup, HD, wa_kT[t], nullptr, usup, B, HD, 0);
        dot_score<<<gupd((size_t)Nv), 256, 0, stream>>>(score, vert, usup, vbatch, Nv);
        seg_softmax_csr<<<gup4(B), 256, 0, stream>>>(score, rp_b, ei, B);
        seg_gather<<<gup4(B), 256, 0, stream>>>(pool, vert, rp_b, ei, nullptr, score,
                                                nullptr, B, HD, 0, 0, 1);
        gemm1(stream, pool, HD, wa_mrg[t], nullptr, msup, B, HD, 1);
        gemm2g(stream, msup, HD, supe, HD, wa_gs[t], bgs, zsup, B, HD, 3, msup, supe);
        gemm1(stream, zsup, HD, wa_sih, gs_bih, gis, B, 3 * HD, 0);
        gemm1(stream, supe, HD, wa_shh, gs_bhh, ghs, B, 3 * HD, 0);
        gru_gate<<<gupd((size_t)B * HD), 256, 0, stream>>>(supe, gis, ghs, B);
    }

    // ---- Group module ------------------------------------------------------
    seg_gather<<<gup4((size_t)NG), 256, 0, stream>>>(grp, vert, rp_c, ei, comp_src,
                                                     nullptr, nullptr, NG, HD, 0, 0, 2);

    // ---- site conv stack ---------------------------------------------------
    float* T1 = T; float* T2 = T + NsH; float* T3 = T + 2 * NsH;
    gemm1(stream, site_x, Fs, wa_s0, nullptr, T1, Ns, HD, 0);
    seg_gather<<<gup4((size_t)Ns), 256, 0, stream>>>(T2, T1, rp_s, ei, site_src,
                                                     nullptr, b_s0, Ns, HD, 0, 1, 0);
    gemm1(stream, T2, HD, wa_s1, nullptr, T1, Ns, HD, 0);
    seg_gather<<<gup4((size_t)Ns), 256, 0, stream>>>(T3, T1, rp_s, ei, site_src,
                                                     nullptr, b_s1, Ns, HD, 0, 1, 0);
    gemm3s(stream, site_x, Fs, T2, HD, T3, HD, wa_so, b_so, site_o, Ns, HD, 1);

    // ---- masf conv stack ---------------------------------------------------
    gemm1(stream, masf_x, Fm, wa_m0, nullptr, T1, Nm, HD, 0);
    seg_gather<<<gup4((size_t)Nm), 256, 0, stream>>>(T2, T1, rp_m, ei, masf_src,
                                                     nullptr, b_m0, Nm, HD, 0, 1, 0);
    gemm1(stream, T2, HD, wa_m1, nullptr, T1, Nm, HD, 0);
    seg_gather<<<gup4((size_t)Nm), 256, 0, stream>>>(T3, T1, rp_m, ei, masf_src,
                                                     nullptr, b_m1, Nm, HD, 0, 1, 0);
    gemm3s(stream, masf_x, Fm, T2, HD, T3, HD, wa_mo, b_mo, masf_o, Nm, HD, 1);

    // ---- anchor pooling ----------------------------------------------------
    seg_gather<<<gup4((size_t)NA), 256, 0, stream>>>(anch, site_o, rp_p, ei, prot_src,
                                                     prot_ea, nullptr, NA, 2 * HD, 0, 0, 3);
    seg_gather<<<gup4((size_t)NA), 256, 0, stream>>>(anch, masf_o, rp_q, ei, prom_src,
                                                     prom_ea, nullptr, NA, 2 * HD, HD, 0, 3);

    // ---- anchor conv stack -------------------------------------------------
    gemm1(stream, anch, 2 * HD, wa_a0, nullptr, axw, NA, HD, 0);
    seg_gather<<<gup4((size_t)NA), 256, 0, stream>>>(ah1, axw, rp_a, ei, anch_src,
                                                     nullptr, b_a0, NA, HD, 0, 1, 0);
    gemm1(stream, ah1, HD, wa_a1, nullptr, axw, NA, HD, 0);
    seg_gather<<<gup4((size_t)NA), 256, 0, stream>>>(ah2, axw, rp_a, ei, anch_src,
                                                     nullptr, b_a1, NA, HD, 0, 1, 0);
    gemm3s(stream, anch, 2 * HD, ah1, HD, ah2, HD, wa_ao, b_ao, aout, NA, HD, 1);

    // ---- distance heads ----------------------------------------------------
    gemm1(stream, aout, HD, wa_ds, b_ds, pa, NA, HD, 1);
    gemm1(stream, grp, HD, wa_dc, b_dc, pg, NG, HD, 1);
    float* outp = (float*)d_out;
    pdist_k<<<gupd((size_t)Pag), 256, 0, stream>>>(outp, pa, pg, ag_a, ag_g, Pag);
    pdist_k<<<gupd((size_t)Paa), 256, 0, stream>>>(outp + Pag, pa, pa, aa0, aa1, Paa);
    pdist_k<<<gupd((size_t)Pgg), 256, 0, stream>>>(outp + Pag + Paa, pg, pg, gg0, gg1, Pgg);
}

// Round 12
// 1310.475 us; speedup vs baseline: 1.0765x; 1.0555x over previous
//
#include <hip/hip_runtime.h>
#include <math.h>

#define HD 128  // hidden dim

typedef __bf16 bf16x8 __attribute__((ext_vector_type(8)));
typedef unsigned short u16x8 __attribute__((ext_vector_type(8)));
typedef float f32x4 __attribute__((ext_vector_type(4)));

__device__ __forceinline__ unsigned short f2bf(float f) {
    unsigned u = __float_as_uint(f);
    unsigned r = u + 0x7FFFu + ((u >> 16) & 1u);   // RTN-even
    return (unsigned short)(r >> 16);
}

// ---------------------------------------------------------------- weight convert
#define MAXW 32
struct WDesc { const float* src; unsigned short* dst; int K, N, Kpad, tr; };
struct WBatch { WDesc d[MAXW]; };

__global__ void convert_weights(WBatch wb)
{
    WDesc d = wb.d[blockIdx.y];
    long total = (long)d.N * d.Kpad;
    long i = (long)blockIdx.x * 256 + threadIdx.x;
    if (i >= total) return;
    int n = (int)(i / d.Kpad), k = (int)(i % d.Kpad);
    float v = 0.f;
    if (k < d.K) v = d.tr ? d.src[(size_t)k * d.N + n] : d.src[(size_t)n * d.K + k];
    d.dst[i] = f2bf(v);
}

// ---------------------------------------------------------------- MFMA GEMM
// C[M,N] = act( [A0|A1|A2] @ W + bias ), W as bf16 WT[N][Kpad].
// act: 0 none, 1 lrelu, 2 sigmoid, 3 gate: C = z*G1 + (1-z)*G2, z=sigmoid(v).
// ridx1: optional row-index for segment A1 (A1 row = ridx1[gr]); g2ridx: G2
// rows indexed by ridx1 too (fuses trans=tsml[vbatch] gather into the gemm).
// 256 thr = 4 waves; tile 64x128; depth-1 register prefetch (round-9 proven:
// deeper pipelines cost occupancy > latency gain on this structure).
// One raw s_barrier/tile, only lgkmcnt drained.
// C/D: col=lane&15, row=(lane>>4)*4+reg  [m89-verified].
__global__ __launch_bounds__(256)
void gemm_mfma(const float* __restrict__ A0, const float* __restrict__ A1,
               const float* __restrict__ A2, int K0, int K1, int K2,
               int lda0, int lda1, int lda2,
               const unsigned short* __restrict__ WT, int Kpad,
               const float* __restrict__ bias, float* __restrict__ C,
               int M, int N, int act,
               const float* __restrict__ G1, const float* __restrict__ G2,
               const int* __restrict__ ridx1, int g2ridx)
{
    __shared__ __align__(16) unsigned short sA[2][64][40];
    __shared__ __align__(16) unsigned short sW[2][128][40];

    const int tid = threadIdx.x;
    const int lane = tid & 63, w = tid >> 6;
    const int mBase = blockIdx.x * 64;
    const int nBase = blockIdx.y * 128;
    const int Ktot = K0 + K1 + K2;
    const int colb = w * 32;
    const int c16 = lane & 15, g = lane >> 4;

    f32x4 acc[4][2];
#pragma unroll
    for (int i = 0; i < 4; ++i)
#pragma unroll
        for (int j = 0; j < 2; ++j) acc[i][j] = (f32x4){0.f, 0.f, 0.f, 0.f};

    const int kTiles = (Ktot + 31) / 32;

    auto loadTile = [&](int kt, float f[8], u16x8& h0, u16x8& h1) {
        const int k0g = kt * 32;
        const float* Ab; int lda, kloc, segK; const int* ri = nullptr;
        if (k0g < K0)           { Ab = A0; lda = lda0; kloc = k0g;           segK = K0; }
        else if (k0g < K0 + K1) { Ab = A1; lda = lda1; kloc = k0g - K0;      segK = K1; ri = ridx1; }
        else                    { Ab = A2; lda = lda2; kloc = k0g - K0 - K1; segK = K2; }
        int row = tid >> 2, kq = (tid & 3) * 8;
        int gr = mBase + row;
        int ar = (ri && gr < M) ? ri[gr] : gr;
        if (gr < M && ((lda & 3) == 0) && (kloc + kq + 8 <= segK)) {
            const float* ap = Ab + (size_t)ar * lda + kloc + kq;
            float4 v0 = *(const float4*)ap, v1 = *(const float4*)(ap + 4);
            f[0] = v0.x; f[1] = v0.y; f[2] = v0.z; f[3] = v0.w;
            f[4] = v1.x; f[5] = v1.y; f[6] = v1.z; f[7] = v1.w;
        } else {
#pragma unroll
            for (int i = 0; i < 8; ++i) {
                int kk = kloc + kq + i;
                f[i] = (gr < M && kk < segK) ? Ab[(size_t)ar * lda + kk] : 0.f;
            }
        }
        int col = tid >> 1, kh = (tid & 1) * 16;
        const unsigned short* wp = WT + (size_t)(nBase + col) * Kpad + k0g + kh;
        h0 = *(const u16x8*)wp;
        h1 = *(const u16x8*)(wp + 8);
    };
    auto stageWrite = [&](int buf, const float f[8], u16x8 h0, u16x8 h1) {
        int row = tid >> 2, kq = (tid & 3) * 8;
        u16x8 h;
#pragma unroll
        for (int i = 0; i < 8; ++i) h[i] = f2bf(f[i]);
        *(u16x8*)&sA[buf][row][kq] = h;
        int col = tid >> 1, kh = (tid & 1) * 16;
        *(u16x8*)&sW[buf][col][kh] = h0;
        *(u16x8*)&sW[buf][col][kh + 8] = h1;
    };
    auto compute = [&](int buf) {
        bf16x8 bfr0 = __builtin_bit_cast(bf16x8, *(const u16x8*)&sW[buf][colb + c16][g * 8]);
        bf16x8 bfr1 = __builtin_bit_cast(bf16x8, *(const u16x8*)&sW[buf][colb + 16 + c16][g * 8]);
#pragma unroll
        for (int rf = 0; rf < 4; ++rf) {
            bf16x8 af = __builtin_bit_cast(bf16x8, *(const u16x8*)&sA[buf][rf * 16 + c16][g * 8]);
            acc[rf][0] = __builtin_amdgcn_mfma_f32_16x16x32_bf16(af, bfr0, acc[rf][0], 0, 0, 0);
            acc[rf][1] = __builtin_amdgcn_mfma_f32_16x16x32_bf16(af, bfr1, acc[rf][1], 0, 0, 0);
        }
    };

    // prologue: stage tile 0, prefetch tile 1
    float fN[8]; u16x8 hN0, hN1;
    {
        float fC[8]; u16x8 hC0, hC1;
        loadTile(0, fC, hC0, hC1);
        stageWrite(0, fC, hC0, hC1);
        if (kTiles > 1) loadTile(1, fN, hN0, hN1);
    }
    asm volatile("s_waitcnt lgkmcnt(0)" ::: "memory");
    __builtin_amdgcn_s_barrier();

    int cur = 0;
#pragma unroll 2
    for (int kt = 0; kt < kTiles; ++kt) {
        float fP[8]; u16x8 hP0, hP1;
        const bool pf = (kt + 2 < kTiles);
        if (pf) loadTile(kt + 2, fP, hP0, hP1);     // issue early: hides under MFMA+stage
        compute(cur);
        if (kt + 1 < kTiles) stageWrite(cur ^ 1, fN, hN0, hN1);
        asm volatile("s_waitcnt lgkmcnt(0)" ::: "memory");
        __builtin_amdgcn_s_barrier();
        if (pf) {
#pragma unroll
            for (int i = 0; i < 8; ++i) fN[i] = fP[i];
            hN0 = hP0; hN1 = hP1;
        }
        cur ^= 1;
    }

    // ---- epilogue
#pragma unroll
    for (int cf = 0; cf < 2; ++cf) {
        int col = nBase + colb + cf * 16 + c16;
        float bb = bias ? bias[col] : 0.f;
#pragma unroll
        for (int rf = 0; rf < 4; ++rf) {
            int r0 = mBase + rf * 16 + g * 4;
#pragma unroll
            for (int r = 0; r < 4; ++r) {
                int gr = r0 + r;
                if (gr >= M) continue;
                size_t o = (size_t)gr * N + col;
                float v = acc[rf][cf][r] + bb;
                if (act == 1) v = v > 0.f ? v : 0.1f * v;
                else if (act == 2) v = 1.f / (1.f + expf(-v));
                else if (act == 3) {
                    float z = 1.f / (1.f + expf(-v));
                    size_t o2 = g2ridx ? ((size_t)ridx1[gr] * N + col) : o;
                    v = z * G1[o] + (1.f - z) * G2[o2];
                }
                C[o] = v;
            }
        }
    }
}

// ---------------------------------------------------------------- CSR build
__global__ void hist_k(int* __restrict__ cnt, const int* __restrict__ dst, int E)
{
    int i = blockIdx.x * 256 + threadIdx.x;
    if (i < E) atomicAdd(&cnt[dst[i]], 1);
}

#define SCB 4096

__global__ __launch_bounds__(256)
void scan_sums(const int* __restrict__ cnt, int n, int* __restrict__ bsum)
{
    __shared__ int red[256];
    int t = threadIdx.x;
    int base = blockIdx.x * SCB + t * 16;
    int s = 0;
#pragma unroll
    for (int i = 0; i < 16; ++i) { int idx = base + i; if (idx < n) s += cnt[idx]; }
    red[t] = s; __syncthreads();
    for (int st = 128; st > 0; st >>= 1) {
        if (t < st) red[t] += red[t + st];
        __syncthreads();
    }
    if (t == 0) bsum[blockIdx.x] = red[0];
}

__global__ void scan_bsum(int* __restrict__ bsum, int nb)
{
    if (threadIdx.x == 0) {
        int run = 0;
        for (int i = 0; i < nb; ++i) { int v = bsum[i]; bsum[i] = run; run += v; }
    }
}

__global__ __launch_bounds__(256)
void scan_write(const int* __restrict__ cnt, int n, const int* __restrict__ bsum,
                int* __restrict__ rp)
{
    __shared__ int a0[256], a1[256];
    int t = threadIdx.x;
    int base = blockIdx.x * SCB + t * 16;
    int v[16]; int s = 0;
#pragma unroll
    for (int i = 0; i < 16; ++i) { int idx = base + i; v[i] = (idx < n) ? cnt[idx] : 0; s += v[i]; }
    a0[t] = s; __syncthreads();
    int* cur = a0; int* nxt = a1;
    for (int st = 1; st < 256; st <<= 1) {
        int val = cur[t] + ((t >= st) ? cur[t - st] : 0);
        nxt[t] = val; __syncthreads();
        int* tmp = cur; cur = nxt; nxt = tmp;
    }
    int run = bsum[blockIdx.x] + (t > 0 ? cur[t - 1] : 0);
#pragma unroll
    for (int i = 0; i < 16; ++i) {
        int idx = base + i;
        if (idx < n) {
            rp[idx] = run; run += v[i];
            if (idx == n - 1) rp[n] = run;
        }
    }
}

__global__ void fill_k(int* __restrict__ eidx, int* __restrict__ cursor,
                       const int* __restrict__ dst, int E)
{
    int i = blockIdx.x * 256 + threadIdx.x;
    if (i < E) eidx[atomicAdd(&cursor[dst[i]], 1)] = i;
}

// ---------------------------------------------------------------- CSR gather
// One wave per destination row; lane covers 2 feats (float2).
// mode 0: w=1   1: w=wattr[e]   2: w=1/deg   3: w=softmax(6-wattr)[e]
__global__ __launch_bounds__(256)
void seg_gather(float* __restrict__ out, const float* __restrict__ X,
                const int* __restrict__ rowptr, const int* __restrict__ eidx,
                const int* __restrict__ src, const float* __restrict__ wattr,
                const float* __restrict__ bias, int n, int ostride, int ooff,
                int act, int mode)
{
    int d = blockIdx.x * 4 + (threadIdx.x >> 6);
    if (d >= n) return;
    int lane = threadIdx.x & 63;
    int lo = rowptr[d], hi = rowptr[d + 1];
    float w0 = 1.f, mx = 0.f, iden = 0.f;
    if (mode == 2) w0 = (hi > lo) ? 1.f / (float)(hi - lo) : 0.f;
    if (mode == 3) {
        float mxl = -1e30f;
        for (int base = lo; base < hi; base += 64) {
            int i = base + lane;
            if (i < hi) mxl = fmaxf(mxl, 6.f - wattr[eidx[i]]);
        }
#pragma unroll
        for (int o = 32; o; o >>= 1) mxl = fmaxf(mxl, __shfl_xor(mxl, o));
        mx = mxl;
        float dl = 0.f;
        for (int base = lo; base < hi; base += 64) {
            int i = base + lane;
            if (i < hi) dl += expf(6.f - wattr[eidx[i]] - mx);
        }
#pragma unroll
        for (int o = 32; o; o >>= 1) dl += __shfl_xor(dl, o);
        iden = 1.f / dl;
    }

    float ax = 0.f, ay = 0.f;
    int i = lo;
    for (; i + 4 <= hi; i += 4) {
        int e0 = eidx[i], e1 = eidx[i + 1], e2 = eidx[i + 2], e3 = eidx[i + 3];
        int s0 = src ? src[e0] : e0, s1 = src ? src[e1] : e1;
        int s2 = src ? src[e2] : e2, s3 = src ? src[e3] : e3;
        float w0v, w1v, w2v, w3v;
        if (mode == 0) { w0v = w1v = w2v = w3v = 1.f; }
        else if (mode == 1) { w0v = wattr[e0]; w1v = wattr[e1]; w2v = wattr[e2]; w3v = wattr[e3]; }
        else if (mode == 2) { w0v = w1v = w2v = w3v = w0; }
        else {
            w0v = expf(6.f - wattr[e0] - mx) * iden;
            w1v = expf(6.f - wattr[e1] - mx) * iden;
            w2v = expf(6.f - wattr[e2] - mx) * iden;
            w3v = expf(6.f - wattr[e3] - mx) * iden;
        }
        float2 v0 = *(const float2*)(X + (size_t)s0 * HD + 2 * lane);
        float2 v1 = *(const float2*)(X + (size_t)s1 * HD + 2 * lane);
        float2 v2 = *(const float2*)(X + (size_t)s2 * HD + 2 * lane);
        float2 v3 = *(const float2*)(X + (size_t)s3 * HD + 2 * lane);
        ax += w0v * v0.x + w1v * v1.x + w2v * v2.x + w3v * v3.x;
        ay += w0v * v0.y + w1v * v1.y + w2v * v2.y + w3v * v3.y;
    }
    for (; i < hi; ++i) {
        int e = eidx[i];
        int s = src ? src[e] : e;
        float w;
        if (mode == 0) w = 1.f;
        else if (mode == 1) w = wattr[e];
        else if (mode == 2) w = w0;
        else w = expf(6.f - wattr[e] - mx) * iden;
        float2 v = *(const float2*)(X + (size_t)s * HD + 2 * lane);
        ax += w * v.x; ay += w * v.y;
    }
    if (bias) { float2 b = *(const float2*)(bias + 2 * lane); ax += b.x; ay += b.y; }
    if (act == 1) { ax = ax > 0.f ? ax : 0.1f * ax; ay = ay > 0.f ? ay : 0.1f * ay; }
    *(float2*)(out + (size_t)d * ostride + ooff + 2 * lane) = make_float2(ax, ay);
}

// ---------------------------------------------------------------- fused segment softmax
__global__ __launch_bounds__(256)
void seg_softmax_csr(float* __restrict__ sc, const int* __restrict__ rowptr,
                     const int* __restrict__ eidx, int n)
{
    int d = blockIdx.x * 4 + (threadIdx.x >> 6);
    if (d >= n) return;
    int lane = threadIdx.x & 63;
    int lo = rowptr[d], hi = rowptr[d + 1];
    float mxl = -1e30f;
    for (int i = lo + lane; i < hi; i += 64) mxl = fmaxf(mxl, sc[eidx[i]]);
#pragma unroll
    for (int o = 32; o; o >>= 1) mxl = fmaxf(mxl, __shfl_xor(mxl, o));
    float dl = 0.f;
    for (int i = lo + lane; i < hi; i += 64) dl += expf(sc[eidx[i]] - mxl);
#pragma unroll
    for (int o = 32; o; o >>= 1) dl += __shfl_xor(dl, o);
    float iden = 1.f / dl;
    for (int i = lo + lane; i < hi; i += 64) {
        int v = eidx[i];
        sc[v] = expf(sc[v] - mxl) * iden;
    }
}

// ---------------------------------------------------------------- misc kernels
__global__ void gru_gate(float* __restrict__ h, const float* __restrict__ gi,
                         const float* __restrict__ gh, int M)
{
    long i = (long)blockIdx.x * 256 + threadIdx.x;
    if (i >= (long)M * HD) return;
    int row = (int)(i >> 7), f = (int)(i & 127);
    size_t o = (size_t)row * 384 + f;
    float r = 1.f / (1.f + expf(-(gi[o] + gh[o])));
    float z = 1.f / (1.f + expf(-(gi[o + 128] + gh[o + 128])));
    float n = tanhf(gi[o + 256] + r * gh[o + 256]);
    h[i] = (1.f - z) * n + z * h[i];
}

// score[v] = dot(vert[v], u[batch[v]]) / sqrt(128)   (u = q @ Wk^T)
__global__ void dot_score(float* __restrict__ sc, const float* __restrict__ vert,
                          const float* __restrict__ u, const int* __restrict__ batch, int n)
{
    int v = blockIdx.x * 256 + threadIdx.x;
    if (v >= n) return;
    const float4* a = (const float4*)(vert + (size_t)v * HD);
    const float4* q = (const float4*)(u + (size_t)batch[v] * HD);
    float acc = 0.f;
#pragma unroll
    for (int i = 0; i < 32; ++i) {
        float4 x = a[i], y = q[i];
        acc += x.x * y.x + x.y * y.y + x.z * y.z + x.w * y.w;
    }
    sc[v] = acc * 0.08838834764831843f;  // 1/sqrt(128)
}

__global__ void pdist_k(float* __restrict__ out, const float* __restrict__ A,
                        const float* __restrict__ Bm, const int* __restrict__ ia,
                        const int* __restrict__ ib, int P)
{
    int p = blockIdx.x * 256 + threadIdx.x;
    if (p >= P) return;
    const float4* a = (const float4*)(A + (size_t)ia[p] * HD);
    const float4* b = (const float4*)(Bm + (size_t)ib[p] * HD);
    float acc = 0.f;
#pragma unroll
    for (int i = 0; i < 32; ++i) {
        float4 x = a[i], y = b[i];
        float d0 = x.x - y.x + 1e-6f, d1 = x.y - y.y + 1e-6f;
        float d2 = x.z - y.z + 1e-6f, d3 = x.w - y.w + 1e-6f;
        acc += d0 * d0 + d1 * d1 + d2 * d2 + d3 * d3;
    }
    out[p] = sqrtf(acc);
}

// ---------------------------------------------------------------- host

static inline unsigned gupd(size_t n) { return (unsigned)((n + 255) / 256); }
static inline unsigned gup4(size_t n) { return (unsigned)((n + 3) / 4); }

struct WArena { unsigned short* p; int Kpad; };

static void gemm3s(hipStream_t st, const float* A0, int K0, const float* A1, int K1,
                   const float* A2, int K2, WArena wa, const float* bias,
                   float* C, int M, int N, int act,
                   const float* G1 = nullptr, const float* G2 = nullptr,
                   const int* ridx1 = nullptr, int g2ridx = 0)
{
    dim3 g((M + 63) / 64, N / 128);
    hipLaunchKernelGGL(gemm_mfma, g, dim3(256), 0, st, A0, A1, A2, K0, K1, K2,
                       K0, K1, K2, wa.p, wa.Kpad, bias, C, M, N, act, G1, G2,
                       ridx1, g2ridx);
}
static void gemm1(hipStream_t st, const float* A, int K, WArena wa, const float* bias,
                  float* C, int M, int N, int act)
{ gemm3s(st, A, K, nullptr, 0, nullptr, 0, wa, bias, C, M, N, act); }

extern "C" void kernel_launch(void* const* d_in, const int* in_sizes, int n_in,
                              void* d_out, int out_size, void* d_ws, size_t ws_size,
                              hipStream_t stream)
{
    (void)n_in; (void)out_size;
    const float* vert_x  = (const float*)d_in[0];
    const float* site_x  = (const float*)d_in[1];
    const float* masf_x  = (const float*)d_in[2];
    const float* prot_ea = (const float*)d_in[3];
    const float* prom_ea = (const float*)d_in[4];
    const int* vert_src = (const int*)d_in[5];
    const int* vert_dst = (const int*)d_in[6];
    const int* vbatch   = (const int*)d_in[7];
    const int* comp_src = (const int*)d_in[8];
    const int* comp_dst = (const int*)d_in[9];
    const int* site_src = (const int*)d_in[10];
    const int* site_dst = (const int*)d_in[11];
    const int* masf_src = (const int*)d_in[12];
    const int* masf_dst = (const int*)d_in[13];
    const int* prot_src = (const int*)d_in[14];
    const int* prot_dst = (const int*)d_in[15];
    const int* prom_src = (const int*)d_in[16];
    const int* prom_dst = (const int*)d_in[17];
    const int* anch_src = (const int*)d_in[18];
    const int* anch_dst = (const int*)d_in[19];
    const int* ag_a = (const int*)d_in[20];
    const int* ag_g = (const int*)d_in[21];
    const int* aa0  = (const int*)d_in[22];
    const int* aa1  = (const int*)d_in[23];
    const int* gg0  = (const int*)d_in[24];
    const int* gg1  = (const int*)d_in[25];
    const float* W_emb = (const float*)d_in[26];
    const float* b_emb = (const float*)d_in[27];
    const float* gW_main = (const float*)d_in[28];
    const float* gW_s2m  = (const float*)d_in[29];
    const float* gW_gm   = (const float*)d_in[30];
    const float* gb_gm   = (const float*)d_in[31];
    const float* gW_q    = (const float*)d_in[32];
    const float* gW_k    = (const float*)d_in[33];
    const float* gW_mrg  = (const float*)d_in[34];
    const float* gW_gs   = (const float*)d_in[35];
    const float* gb_gs   = (const float*)d_in[36];
    const float* gm_Wih = (const float*)d_in[37];
    const float* gm_Whh = (const float*)d_in[38];
    const float* gm_bih = (const float*)d_in[39];
    const float* gm_bhh = (const float*)d_in[40];
    const float* gs_Wih = (const float*)d_in[41];
    const float* gs_Whh = (const float*)d_in[42];
    const float* gs_bih = (const float*)d_in[43];
    const float* gs_bhh = (const float*)d_in[44];
    const float* W_s0 = (const float*)d_in[45];
    const float* b_s0 = (const float*)d_in[46];
    const float* W_s1 = (const float*)d_in[47];
    const float* b_s1 = (const float*)d_in[48];
    const float* W_so = (const float*)d_in[49];
    const float* b_so = (const float*)d_in[50];
    const float* W_m0 = (const float*)d_in[51];
    const float* b_m0 = (const float*)d_in[52];
    const float* W_m1 = (const float*)d_in[53];
    const float* b_m1 = (const float*)d_in[54];
    const float* W_mo = (const float*)d_in[55];
    const float* b_mo = (const float*)d_in[56];
    const float* W_a0 = (const float*)d_in[57];
    const float* b_a0 = (const float*)d_in[58];
    const float* W_a1 = (const float*)d_in[59];
    const float* b_a1 = (const float*)d_in[60];
    const float* W_ao = (const float*)d_in[61];
    const float* b_ao = (const float*)d_in[62];
    const float* W_ds = (const float*)d_in[63];
    const float* b_ds = (const float*)d_in[64];
    const float* W_dc = (const float*)d_in[65];
    const float* b_dc = (const float*)d_in[66];

    const int B = 256, NG = 4000, NA = 10000, Ns = 80000, Nm = 80000;
    const int Nv = in_sizes[7];
    const int FV = in_sizes[0] / Nv;
    const int Fs = in_sizes[1] / Ns;
    const int Fm = in_sizes[2] / Nm;
    const int Ev = in_sizes[5], Ec = in_sizes[8], Es = in_sizes[10], Em = in_sizes[12];
    const int Ep = in_sizes[14], Ea = in_sizes[18];
    const int Pag = in_sizes[20], Paa = in_sizes[22], Pgg = in_sizes[24];
    const int D = in_sizes[28] / (HD * HD);

    // ---- workspace layout (floats) --------------------------------------
    float* ws = (float*)d_ws;
    size_t off = 0;
    auto take = [&](size_t n) { size_t o = off; off += n; return o; };
    float* vert  = ws + take((size_t)Nv * HD);
    float* supe  = ws + take((size_t)B * HD);
    float* qsup  = ws + take((size_t)B * HD);
    float* usup  = ws + take((size_t)B * HD);
    float* pool  = ws + take((size_t)B * HD);
    float* msup  = ws + take((size_t)B * HD);
    float* zsup  = ws + take((size_t)B * HD);
    float* gis   = ws + take((size_t)B * 3 * HD);
    float* ghs   = ws + take((size_t)B * 3 * HD);
    float* tsml  = ws + take((size_t)B * HD);
    float* grp   = ws + take((size_t)NG * HD);
    float* site_o = ws + take((size_t)Ns * HD);
    float* masf_o = ws + take((size_t)Nm * HD);
    float* anch  = ws + take((size_t)NA * 2 * HD);
    float* ah1   = ws + take((size_t)NA * HD);
    float* ah2   = ws + take((size_t)NA * HD);
    float* axw   = ws + take((size_t)NA * HD);
    float* aout  = ws + take((size_t)NA * HD);
    float* pa    = ws + take((size_t)NA * HD);
    float* pg    = ws + take((size_t)NG * HD);
    float* score = ws + take((size_t)Nv);
    const size_t NvH = (size_t)Nv * HD, NsH = (size_t)Ns * HD;
    float* T = ws + take(3 * NsH);   // shared temp region

    // ---- CSR arrays (ints), concatenated layout --------------------------
    const int nN[8] = {Nv, NG, Ns, Nm, NA, NA, NA, B};
    const int nE[8] = {Ev, Ec, Es, Em, Ep, Ep, Ea, Nv};
    const int* dsts[8] = {vert_dst, comp_dst, site_dst, masf_dst,
                          prot_dst, prom_dst, anch_dst, vbatch};
    int baseN[9], baseE[9];
    baseN[0] = 0; baseE[0] = 0;
    for (int g = 0; g < 8; ++g) { baseN[g + 1] = baseN[g] + nN[g]; baseE[g + 1] = baseE[g] + nE[g]; }
    const int totN = baseN[8], totE = baseE[8];

    int* ib = (int*)(ws + off);
    size_t ioff = 0;
    auto taki = [&](size_t n) { size_t o = ioff; ioff += n; return o; };
    int* cnt_all = ib + taki((size_t)totN);
    int* rp_all  = ib + taki((size_t)totN + 1);
    int* cur_all = ib + taki((size_t)totN);
    int* ei_all  = ib + taki((size_t)totE);
    int* bsum    = ib + taki((size_t)((totN + SCB - 1) / SCB) + 1);
    ioff = (ioff + 7) & ~(size_t)7;   // 16B-align the bf16 arena

    // ---- bf16 weight arenas ----------------------------------------------
    unsigned short* warena = (unsigned short*)(ib + ioff);
    size_t woff = 0;
    WBatch wb; int nW = 0; long maxWTot = 0;
    auto reg = [&](const float* src, int K, int N, int tr) {
        int Kpad = (K + 31) & ~31;
        unsigned short* dst = warena + woff;
        woff += (size_t)N * Kpad;
        long tot = (long)N * Kpad; if (tot > maxWTot) maxWTot = tot;
        wb.d[nW].src = src; wb.d[nW].dst = dst; wb.d[nW].K = K;
        wb.d[nW].N = N; wb.d[nW].Kpad = Kpad; wb.d[nW].tr = tr;
        ++nW;
        WArena a; a.p = dst; a.Kpad = Kpad; return a;
    };
    WArena wa_emb = reg(W_emb, FV, HD, 1);
    WArena wa_main[2], wa_s2m[2], wa_gm[2], wa_q[2], wa_kT[2], wa_mrg[2], wa_gs[2];
    for (int t = 0; t < D && t < 2; ++t) {
        wa_main[t] = reg(gW_main + (size_t)t * HD * HD, HD, HD, 1);
        wa_s2m[t]  = reg(gW_s2m  + (size_t)t * HD * HD, HD, HD, 1);
        wa_gm[t]   = reg(gW_gm   + (size_t)t * 2 * HD * HD, 2 * HD, HD, 1);
        wa_q[t]    = reg(gW_q    + (size_t)t * HD * HD, HD, HD, 1);
        wa_kT[t]   = reg(gW_k    + (size_t)t * HD * HD, HD, HD, 0);  // u = q @ Wk^T
        wa_mrg[t]  = reg(gW_mrg  + (size_t)t * HD * HD, HD, HD, 1);
        wa_gs[t]   = reg(gW_gs   + (size_t)t * 2 * HD * HD, 2 * HD, HD, 1);
    }
    WArena wa_mih = reg(gm_Wih, HD, 3 * HD, 0);   // GRU: x@Wih.T -> WT = Wih as-is
    WArena wa_mhh = reg(gm_Whh, HD, 3 * HD, 0);
    WArena wa_sih = reg(gs_Wih, HD, 3 * HD, 0);
    WArena wa_shh = reg(gs_Whh, HD, 3 * HD, 0);
    WArena wa_s0 = reg(W_s0, Fs, HD, 1);
    WArena wa_s1 = reg(W_s1, HD, HD, 1);
    WArena wa_so = reg(W_so, Fs + 2 * HD, HD, 1);
    WArena wa_m0 = reg(W_m0, Fm, HD, 1);
    WArena wa_m1 = reg(W_m1, HD, HD, 1);
    WArena wa_mo = reg(W_mo, Fm + 2 * HD, HD, 1);
    WArena wa_a0 = reg(W_a0, 2 * HD, HD, 1);
    WArena wa_a1 = reg(W_a1, HD, HD, 1);
    WArena wa_ao = reg(W_ao, 4 * HD, HD, 1);
    WArena wa_ds = reg(W_ds, HD, HD, 1);
    WArena wa_dc = reg(W_dc, HD, HD, 1);

    if (ws_size < off * sizeof(float) + ioff * sizeof(int) + woff * sizeof(unsigned short))
        return;

    {
        dim3 g((unsigned)((maxWTot + 255) / 256), nW);
        hipLaunchKernelGGL(convert_weights, g, dim3(256), 0, stream, wb);
    }

    // ---- CSR build --------------------------------------------------------
    hipMemsetAsync(cnt_all, 0, (size_t)totN * sizeof(int), stream);
    for (int g = 0; g < 8; ++g)
        hist_k<<<gupd((size_t)nE[g]), 256, 0, stream>>>(cnt_all + baseN[g], dsts[g], nE[g]);
    const int nScanBlocks = (totN + SCB - 1) / SCB;
    scan_sums<<<nScanBlocks, 256, 0, stream>>>(cnt_all, totN, bsum);
    scan_bsum<<<1, 64, 0, stream>>>(bsum, nScanBlocks);
    scan_write<<<nScanBlocks, 256, 0, stream>>>(cnt_all, totN, bsum, rp_all);
    hipMemcpyAsync(cur_all, rp_all, (size_t)totN * sizeof(int), hipMemcpyDeviceToDevice, stream);
    for (int g = 0; g < 8; ++g)
        fill_k<<<gupd((size_t)nE[g]), 256, 0, stream>>>(ei_all, cur_all + baseN[g], dsts[g], nE[g]);

    const int* rp_v = rp_all + baseN[0];
    const int* rp_c = rp_all + baseN[1];
    const int* rp_s = rp_all + baseN[2];
    const int* rp_m = rp_all + baseN[3];
    const int* rp_p = rp_all + baseN[4];
    const int* rp_q = rp_all + baseN[5];
    const int* rp_a = rp_all + baseN[6];
    const int* rp_b = rp_all + baseN[7];
    const int* ei = ei_all;

    // ---- embedding + super-node init ------------------------------------
    gemm1(stream, vert_x, FV, wa_emb, b_emb, vert, Nv, HD, 1);
    seg_gather<<<gup4(B), 256, 0, stream>>>(supe, vert, rp_b, ei, nullptr, nullptr,
                                            nullptr, B, HD, 0, 0, 0);

    // ---- GWM iterations ---------------------------------------------------
    float* Ta = T;            float* Tb = T + NvH;
    float* Td = T + 3 * NvH;  float* Te = T + 4 * NvH; float* Tf = T + 7 * NvH;
    for (int t = 0; t < D; ++t) {
        const float* bgm = gb_gm + (size_t)t * HD;
        const float* bgs = gb_gs + (size_t)t * HD;

        gemm1(stream, vert, HD, wa_main[t], nullptr, Ta, Nv, HD, 0);
        seg_gather<<<gup4((size_t)Nv), 256, 0, stream>>>(Tb, Ta, rp_v, ei, vert_src,
                                                         nullptr, nullptr, Nv, HD, 0, 1, 0);
        gemm1(stream, supe, HD, wa_s2m[t], nullptr, tsml, B, HD, 1);
        // gate gemm with fused trans gather: A1/G2 rows = tsml[vbatch[row]]
        gemm3s(stream, Tb, HD, tsml, HD, nullptr, 0, wa_gm[t], bgm, Td, Nv, HD, 3,
               Tb, tsml, vbatch, 1);
        gemm1(stream, Td, HD, wa_mih, gm_bih, Te, Nv, 3 * HD, 0);
        gemm1(stream, vert, HD, wa_mhh, gm_bhh, Tf, Nv, 3 * HD, 0);
        gru_gate<<<gupd(NvH), 256, 0, stream>>>(vert, Te, Tf, Nv);
        // attention: u_b = (supe@Wq) @ Wk^T  (tiny), score = vert . u[batch]
        gemm1(stream, supe, HD, wa_q[t], nullptr, qsup, B, HD, 0);
        gemm1(stream, qsup, HD, wa_kT[t], nullptr, usup, B, HD, 0);
        dot_score<<<gupd((size_t)Nv), 256, 0, stream>>>(score, vert, usup, vbatch, Nv);
        seg_softmax_csr<<<gup4(B), 256, 0, stream>>>(score, rp_b, ei, B);
        seg_gather<<<gup4(B), 256, 0, stream>>>(pool, vert, rp_b, ei, nullptr, score,
                                                nullptr, B, HD, 0, 0, 1);
        gemm1(stream, pool, HD, wa_mrg[t], nullptr, msup, B, HD, 1);
        gemm3s(stream, msup, HD, supe, HD, nullptr, 0, wa_gs[t], bgs, zsup, B, HD, 3,
               msup, supe, nullptr, 0);
        gemm1(stream, zsup, HD, wa_sih, gs_bih, gis, B, 3 * HD, 0);
        gemm1(stream, supe, HD, wa_shh, gs_bhh, ghs, B, 3 * HD, 0);
        gru_gate<<<gupd((size_t)B * HD), 256, 0, stream>>>(supe, gis, ghs, B);
    }

    // ---- Group module ------------------------------------------------------
    seg_gather<<<gup4((size_t)NG), 256, 0, stream>>>(grp, vert, rp_c, ei, comp_src,
                                                     nullptr, nullptr, NG, HD, 0, 0, 2);

    // ---- site conv stack ---------------------------------------------------
    float* T1 = T; float* T2 = T + NsH; float* T3 = T + 2 * NsH;
    gemm1(stream, site_x, Fs, wa_s0, nullptr, T1, Ns, HD, 0);
    seg_gather<<<gup4((size_t)Ns), 256, 0, stream>>>(T2, T1, rp_s, ei, site_src,
                                                     nullptr, b_s0, Ns, HD, 0, 1, 0);
    gemm1(stream, T2, HD, wa_s1, nullptr, T1, Ns, HD, 0);
    seg_gather<<<gup4((size_t)Ns), 256, 0, stream>>>(T3, T1, rp_s, ei, site_src,
                                                     nullptr, b_s1, Ns, HD, 0, 1, 0);
    gemm3s(stream, site_x, Fs, T2, HD, T3, HD, wa_so, b_so, site_o, Ns, HD, 1);

    // ---- masf conv stack ---------------------------------------------------
    gemm1(stream, masf_x, Fm, wa_m0, nullptr, T1, Nm, HD, 0);
    seg_gather<<<gup4((size_t)Nm), 256, 0, stream>>>(T2, T1, rp_m, ei, masf_src,
                                                     nullptr, b_m0, Nm, HD, 0, 1, 0);
    gemm1(stream, T2, HD, wa_m1, nullptr, T1, Nm, HD, 0);
    seg_gather<<<gup4((size_t)Nm), 256, 0, stream>>>(T3, T1, rp_m, ei, masf_src,
                                                     nullptr, b_m1, Nm, HD, 0, 1, 0);
    gemm3s(stream, masf_x, Fm, T2, HD, T3, HD, wa_mo, b_mo, masf_o, Nm, HD, 1);

    // ---- anchor pooling ----------------------------------------------------
    seg_gather<<<gup4((size_t)NA), 256, 0, stream>>>(anch, site_o, rp_p, ei, prot_src,
                                                     prot_ea, nullptr, NA, 2 * HD, 0, 0, 3);
    seg_gather<<<gup4((size_t)NA), 256, 0, stream>>>(anch, masf_o, rp_q, ei, prom_src,
                                                     prom_ea, nullptr, NA, 2 * HD, HD, 0, 3);

    // ---- anchor conv stack -------------------------------------------------
    gemm1(stream, anch, 2 * HD, wa_a0, nullptr, axw, NA, HD, 0);
    seg_gather<<<gup4((size_t)NA), 256, 0, stream>>>(ah1, axw, rp_a, ei, anch_src,
                                                     nullptr, b_a0, NA, HD, 0, 1, 0);
    gemm1(stream, ah1, HD, wa_a1, nullptr, axw, NA, HD, 0);
    seg_gather<<<gup4((size_t)NA), 256, 0, stream>>>(ah2, axw, rp_a, ei, anch_src,
                                                     nullptr, b_a1, NA, HD, 0, 1, 0);
    gemm3s(stream, anch, 2 * HD, ah1, HD, ah2, HD, wa_ao, b_ao, aout, NA, HD, 1);

    // ---- distance heads ----------------------------------------------------
    gemm1(stream, aout, HD, wa_ds, b_ds, pa, NA, HD, 1);
    gemm1(stream, grp, HD, wa_dc, b_dc, pg, NG, HD, 1);
    float* outp = (float*)d_out;
    pdist_k<<<gupd((size_t)Pag), 256, 0, stream>>>(outp, pa, pg, ag_a, ag_g, Pag);
    pdist_k<<<gupd((size_t)Paa), 256, 0, stream>>>(outp + Pag, pa, pa, aa0, aa1, Paa);
    pdist_k<<<gupd((size_t)Pgg), 256, 0, stream>>>(outp + Pag + Paa, pg, pg, gg0, gg1, Pgg);
}

// Round 13
// 1268.704 us; speedup vs baseline: 1.1119x; 1.0329x over previous
//
#include <hip/hip_runtime.h>
#include <math.h>

#define HD 128  // hidden dim

typedef __bf16 bf16x8 __attribute__((ext_vector_type(8)));
typedef unsigned short u16x8 __attribute__((ext_vector_type(8)));
typedef float f32x4 __attribute__((ext_vector_type(4)));

__device__ __forceinline__ unsigned short f2bf(float f) {
    unsigned u = __float_as_uint(f);
    unsigned r = u + 0x7FFFu + ((u >> 16) & 1u);   // RTN-even
    return (unsigned short)(r >> 16);
}

// ---------------------------------------------------------------- weight convert
#define MAXW 32
struct WDesc { const float* src; unsigned short* dst; int K, N, Kpad, tr; };
struct WBatch { WDesc d[MAXW]; };

__global__ void convert_weights(WBatch wb)
{
    WDesc d = wb.d[blockIdx.y];
    long total = (long)d.N * d.Kpad;
    long i = (long)blockIdx.x * 256 + threadIdx.x;
    if (i >= total) return;
    int n = (int)(i / d.Kpad), k = (int)(i % d.Kpad);
    float v = 0.f;
    if (k < d.K) v = d.tr ? d.src[(size_t)k * d.N + n] : d.src[(size_t)n * d.K + k];
    d.dst[i] = f2bf(v);
}

// ---------------------------------------------------------------- MFMA GEMM
// C[M,N] = act( [A0|A1|A2] @ W + bias ), W as bf16 WT[N][Kpad].
// act: 0 none, 1 lrelu, 2 sigmoid, 3 gate: C = z*G1 + (1-z)*G2, z=sigmoid(v).
// ridx1: row-index for segment A1 (and G2 when g2ridx) - fuses gathers.
// BMT = 64 (M-large) or 32 (M-small: doubles grid, 6 blocks/CU - GWM gemms
// were 1.2 blocks/CU at BM=64). Depth-1 register prefetch (proven best;
// deeper pipelines cost occupancy > latency gain). One raw s_barrier/tile,
// only lgkmcnt drained. C/D: col=lane&15, row=(lane>>4)*4+reg [m89-verified].
template<int BMT>
__global__ __launch_bounds__(256)
void gemm_mfma_t(const float* __restrict__ A0, const float* __restrict__ A1,
                 const float* __restrict__ A2, int K0, int K1, int K2,
                 int lda0, int lda1, int lda2,
                 const unsigned short* __restrict__ WT, int Kpad,
                 const float* __restrict__ bias, float* __restrict__ C,
                 int M, int N, int act,
                 const float* __restrict__ G1, const float* __restrict__ G2,
                 const int* __restrict__ ridx1, int g2ridx)
{
    constexpr int NRF = BMT / 16;           // row fragments per wave
    __shared__ __align__(16) unsigned short sA[2][BMT][40];
    __shared__ __align__(16) unsigned short sW[2][128][40];

    const int tid = threadIdx.x;
    const int lane = tid & 63, w = tid >> 6;
    const int mBase = blockIdx.x * BMT;
    const int nBase = blockIdx.y * 128;
    const int Ktot = K0 + K1 + K2;
    const int colb = w * 32;
    const int c16 = lane & 15, g = lane >> 4;

    f32x4 acc[NRF][2];
#pragma unroll
    for (int i = 0; i < NRF; ++i)
#pragma unroll
        for (int j = 0; j < 2; ++j) acc[i][j] = (f32x4){0.f, 0.f, 0.f, 0.f};

    const int kTiles = (Ktot + 31) / 32;
    const bool aLoader = (BMT == 64) || (tid < 128);   // BMT*32 elems, 8/thread

    auto loadTile = [&](int kt, float f[8], u16x8& h0, u16x8& h1) {
        const int k0g = kt * 32;
        const float* Ab; int lda, kloc, segK; const int* ri = nullptr;
        if (k0g < K0)           { Ab = A0; lda = lda0; kloc = k0g;           segK = K0; }
        else if (k0g < K0 + K1) { Ab = A1; lda = lda1; kloc = k0g - K0;      segK = K1; ri = ridx1; }
        else                    { Ab = A2; lda = lda2; kloc = k0g - K0 - K1; segK = K2; }
        if (aLoader) {
            int row = tid >> 2, kq = (tid & 3) * 8;
            int gr = mBase + row;
            int ar = (ri && gr < M) ? ri[gr] : gr;
            if (gr < M && ((lda & 3) == 0) && (kloc + kq + 8 <= segK)) {
                const float* ap = Ab + (size_t)ar * lda + kloc + kq;
                float4 v0 = *(const float4*)ap, v1 = *(const float4*)(ap + 4);
                f[0] = v0.x; f[1] = v0.y; f[2] = v0.z; f[3] = v0.w;
                f[4] = v1.x; f[5] = v1.y; f[6] = v1.z; f[7] = v1.w;
            } else {
#pragma unroll
                for (int i = 0; i < 8; ++i) {
                    int kk = kloc + kq + i;
                    f[i] = (gr < M && kk < segK) ? Ab[(size_t)ar * lda + kk] : 0.f;
                }
            }
        }
        int col = tid >> 1, kh = (tid & 1) * 16;
        const unsigned short* wp = WT + (size_t)(nBase + col) * Kpad + k0g + kh;
        h0 = *(const u16x8*)wp;
        h1 = *(const u16x8*)(wp + 8);
    };
    auto stageWrite = [&](int buf, const float f[8], u16x8 h0, u16x8 h1) {
        if (aLoader) {
            int row = tid >> 2, kq = (tid & 3) * 8;
            u16x8 h;
#pragma unroll
            for (int i = 0; i < 8; ++i) h[i] = f2bf(f[i]);
            *(u16x8*)&sA[buf][row][kq] = h;
        }
        int col = tid >> 1, kh = (tid & 1) * 16;
        *(u16x8*)&sW[buf][col][kh] = h0;
        *(u16x8*)&sW[buf][col][kh + 8] = h1;
    };
    auto compute = [&](int buf) {
        bf16x8 bfr0 = __builtin_bit_cast(bf16x8, *(const u16x8*)&sW[buf][colb + c16][g * 8]);
        bf16x8 bfr1 = __builtin_bit_cast(bf16x8, *(const u16x8*)&sW[buf][colb + 16 + c16][g * 8]);
#pragma unroll
        for (int rf = 0; rf < NRF; ++rf) {
            bf16x8 af = __builtin_bit_cast(bf16x8, *(const u16x8*)&sA[buf][rf * 16 + c16][g * 8]);
            acc[rf][0] = __builtin_amdgcn_mfma_f32_16x16x32_bf16(af, bfr0, acc[rf][0], 0, 0, 0);
            acc[rf][1] = __builtin_amdgcn_mfma_f32_16x16x32_bf16(af, bfr1, acc[rf][1], 0, 0, 0);
        }
    };

    // prologue: stage tile 0, prefetch tile 1
    float fN[8]; u16x8 hN0, hN1;
    {
        float fC[8]; u16x8 hC0, hC1;
        loadTile(0, fC, hC0, hC1);
        stageWrite(0, fC, hC0, hC1);
        if (kTiles > 1) loadTile(1, fN, hN0, hN1);
    }
    asm volatile("s_waitcnt lgkmcnt(0)" ::: "memory");
    __builtin_amdgcn_s_barrier();

    int cur = 0;
#pragma unroll 2
    for (int kt = 0; kt < kTiles; ++kt) {
        float fP[8]; u16x8 hP0, hP1;
        const bool pf = (kt + 2 < kTiles);
        if (pf) loadTile(kt + 2, fP, hP0, hP1);     // issue early: hides under MFMA+stage
        compute(cur);
        if (kt + 1 < kTiles) stageWrite(cur ^ 1, fN, hN0, hN1);
        asm volatile("s_waitcnt lgkmcnt(0)" ::: "memory");
        __builtin_amdgcn_s_barrier();
        if (pf) {
#pragma unroll
            for (int i = 0; i < 8; ++i) fN[i] = fP[i];
            hN0 = hP0; hN1 = hP1;
        }
        cur ^= 1;
    }

    // ---- epilogue
#pragma unroll
    for (int cf = 0; cf < 2; ++cf) {
        int col = nBase + colb + cf * 16 + c16;
        float bb = bias ? bias[col] : 0.f;
#pragma unroll
        for (int rf = 0; rf < NRF; ++rf) {
            int r0 = mBase + rf * 16 + g * 4;
#pragma unroll
            for (int r = 0; r < 4; ++r) {
                int gr = r0 + r;
                if (gr >= M) continue;
                size_t o = (size_t)gr * N + col;
                float v = acc[rf][cf][r] + bb;
                if (act == 1) v = v > 0.f ? v : 0.1f * v;
                else if (act == 2) v = 1.f / (1.f + expf(-v));
                else if (act == 3) {
                    float z = 1.f / (1.f + expf(-v));
                    size_t o2 = g2ridx ? ((size_t)ridx1[gr] * N + col) : o;
                    v = z * G1[o] + (1.f - z) * G2[o2];
                }
                C[o] = v;
            }
        }
    }
}

// ---------------------------------------------------------------- CSR build
__global__ void hist_k(int* __restrict__ cnt, const int* __restrict__ dst, int E)
{
    int i = blockIdx.x * 256 + threadIdx.x;
    if (i < E) atomicAdd(&cnt[dst[i]], 1);
}

#define SCB 4096

__global__ __launch_bounds__(256)
void scan_sums(const int* __restrict__ cnt, int n, int* __restrict__ bsum)
{
    __shared__ int red[256];
    int t = threadIdx.x;
    int base = blockIdx.x * SCB + t * 16;
    int s = 0;
#pragma unroll
    for (int i = 0; i < 16; ++i) { int idx = base + i; if (idx < n) s += cnt[idx]; }
    red[t] = s; __syncthreads();
    for (int st = 128; st > 0; st >>= 1) {
        if (t < st) red[t] += red[t + st];
        __syncthreads();
    }
    if (t == 0) bsum[blockIdx.x] = red[0];
}

__global__ void scan_bsum(int* __restrict__ bsum, int nb)
{
    if (threadIdx.x == 0) {
        int run = 0;
        for (int i = 0; i < nb; ++i) { int v = bsum[i]; bsum[i] = run; run += v; }
    }
}

__global__ __launch_bounds__(256)
void scan_write(const int* __restrict__ cnt, int n, const int* __restrict__ bsum,
                int* __restrict__ rp)
{
    __shared__ int a0[256], a1[256];
    int t = threadIdx.x;
    int base = blockIdx.x * SCB + t * 16;
    int v[16]; int s = 0;
#pragma unroll
    for (int i = 0; i < 16; ++i) { int idx = base + i; v[i] = (idx < n) ? cnt[idx] : 0; s += v[i]; }
    a0[t] = s; __syncthreads();
    int* cur = a0; int* nxt = a1;
    for (int st = 1; st < 256; st <<= 1) {
        int val = cur[t] + ((t >= st) ? cur[t - st] : 0);
        nxt[t] = val; __syncthreads();
        int* tmp = cur; cur = nxt; nxt = tmp;
    }
    int run = bsum[blockIdx.x] + (t > 0 ? cur[t - 1] : 0);
#pragma unroll
    for (int i = 0; i < 16; ++i) {
        int idx = base + i;
        if (idx < n) {
            rp[idx] = run; run += v[i];
            if (idx == n - 1) rp[n] = run;
        }
    }
}

__global__ void fill_k(int* __restrict__ eidx, int* __restrict__ cursor,
                       const int* __restrict__ dst, int E)
{
    int i = blockIdx.x * 256 + threadIdx.x;
    if (i < E) eidx[atomicAdd(&cursor[dst[i]], 1)] = i;
}

// ---------------------------------------------------------------- CSR gather
// One wave per destination row; lane covers 2 feats (float2).
// mode 0: w=1   1: w=wattr[e]   2: w=1/deg   3: w=softmax(6-wattr)[e]
__global__ __launch_bounds__(256)
void seg_gather(float* __restrict__ out, const float* __restrict__ X,
                const int* __restrict__ rowptr, const int* __restrict__ eidx,
                const int* __restrict__ src, const float* __restrict__ wattr,
                const float* __restrict__ bias, int n, int ostride, int ooff,
                int act, int mode)
{
    int d = blockIdx.x * 4 + (threadIdx.x >> 6);
    if (d >= n) return;
    int lane = threadIdx.x & 63;
    int lo = rowptr[d], hi = rowptr[d + 1];
    float w0 = 1.f, mx = 0.f, iden = 0.f;
    if (mode == 2) w0 = (hi > lo) ? 1.f / (float)(hi - lo) : 0.f;
    if (mode == 3) {
        float mxl = -1e30f;
        for (int base = lo; base < hi; base += 64) {
            int i = base + lane;
            if (i < hi) mxl = fmaxf(mxl, 6.f - wattr[eidx[i]]);
        }
#pragma unroll
        for (int o = 32; o; o >>= 1) mxl = fmaxf(mxl, __shfl_xor(mxl, o));
        mx = mxl;
        float dl = 0.f;
        for (int base = lo; base < hi; base += 64) {
            int i = base + lane;
            if (i < hi) dl += expf(6.f - wattr[eidx[i]] - mx);
        }
#pragma unroll
        for (int o = 32; o; o >>= 1) dl += __shfl_xor(dl, o);
        iden = 1.f / dl;
    }

    float ax = 0.f, ay = 0.f;
    int i = lo;
    for (; i + 4 <= hi; i += 4) {
        int e0 = eidx[i], e1 = eidx[i + 1], e2 = eidx[i + 2], e3 = eidx[i + 3];
        int s0 = src ? src[e0] : e0, s1 = src ? src[e1] : e1;
        int s2 = src ? src[e2] : e2, s3 = src ? src[e3] : e3;
        float w0v, w1v, w2v, w3v;
        if (mode == 0) { w0v = w1v = w2v = w3v = 1.f; }
        else if (mode == 1) { w0v = wattr[e0]; w1v = wattr[e1]; w2v = wattr[e2]; w3v = wattr[e3]; }
        else if (mode == 2) { w0v = w1v = w2v = w3v = w0; }
        else {
            w0v = expf(6.f - wattr[e0] - mx) * iden;
            w1v = expf(6.f - wattr[e1] - mx) * iden;
            w2v = expf(6.f - wattr[e2] - mx) * iden;
            w3v = expf(6.f - wattr[e3] - mx) * iden;
        }
        float2 v0 = *(const float2*)(X + (size_t)s0 * HD + 2 * lane);
        float2 v1 = *(const float2*)(X + (size_t)s1 * HD + 2 * lane);
        float2 v2 = *(const float2*)(X + (size_t)s2 * HD + 2 * lane);
        float2 v3 = *(const float2*)(X + (size_t)s3 * HD + 2 * lane);
        ax += w0v * v0.x + w1v * v1.x + w2v * v2.x + w3v * v3.x;
        ay += w0v * v0.y + w1v * v1.y + w2v * v2.y + w3v * v3.y;
    }
    for (; i < hi; ++i) {
        int e = eidx[i];
        int s = src ? src[e] : e;
        float w;
        if (mode == 0) w = 1.f;
        else if (mode == 1) w = wattr[e];
        else if (mode == 2) w = w0;
        else w = expf(6.f - wattr[e] - mx) * iden;
        float2 v = *(const float2*)(X + (size_t)s * HD + 2 * lane);
        ax += w * v.x; ay += w * v.y;
    }
    if (bias) { float2 b = *(const float2*)(bias + 2 * lane); ax += b.x; ay += b.y; }
    if (act == 1) { ax = ax > 0.f ? ax : 0.1f * ax; ay = ay > 0.f ? ay : 0.1f * ay; }
    *(float2*)(out + (size_t)d * ostride + ooff + 2 * lane) = make_float2(ax, ay);
}

// ---------------------------------------------------------------- fused segment softmax
__global__ __launch_bounds__(256)
void seg_softmax_csr(float* __restrict__ sc, const int* __restrict__ rowptr,
                     const int* __restrict__ eidx, int n)
{
    int d = blockIdx.x * 4 + (threadIdx.x >> 6);
    if (d >= n) return;
    int lane = threadIdx.x & 63;
    int lo = rowptr[d], hi = rowptr[d + 1];
    float mxl = -1e30f;
    for (int i = lo + lane; i < hi; i += 64) mxl = fmaxf(mxl, sc[eidx[i]]);
#pragma unroll
    for (int o = 32; o; o >>= 1) mxl = fmaxf(mxl, __shfl_xor(mxl, o));
    float dl = 0.f;
    for (int i = lo + lane; i < hi; i += 64) dl += expf(sc[eidx[i]] - mxl);
#pragma unroll
    for (int o = 32; o; o >>= 1) dl += __shfl_xor(dl, o);
    float iden = 1.f / dl;
    for (int i = lo + lane; i < hi; i += 64) {
        int v = eidx[i];
        sc[v] = expf(sc[v] - mxl) * iden;
    }
}

// ---------------------------------------------------------------- misc kernels
__global__ void gru_gate(float* __restrict__ h, const float* __restrict__ gi,
                         const float* __restrict__ gh, int M)
{
    long i = (long)blockIdx.x * 256 + threadIdx.x;
    if (i >= (long)M * HD) return;
    int row = (int)(i >> 7), f = (int)(i & 127);
    size_t o = (size_t)row * 384 + f;
    float r = 1.f / (1.f + expf(-(gi[o] + gh[o])));
    float z = 1.f / (1.f + expf(-(gi[o + 128] + gh[o + 128])));
    float n = tanhf(gi[o + 256] + r * gh[o + 256]);
    h[i] = (1.f - z) * n + z * h[i];
}

// score[v] = dot(vert[v], u[batch[v]]) / sqrt(128)   (u = q @ Wk^T)
__global__ void dot_score(float* __restrict__ sc, const float* __restrict__ vert,
                          const float* __restrict__ u, const int* __restrict__ batch, int n)
{
    int v = blockIdx.x * 256 + threadIdx.x;
    if (v >= n) return;
    const float4* a = (const float4*)(vert + (size_t)v * HD);
    const float4* q = (const float4*)(u + (size_t)batch[v] * HD);
    float acc = 0.f;
#pragma unroll
    for (int i = 0; i < 32; ++i) {
        float4 x = a[i], y = q[i];
        acc += x.x * y.x + x.y * y.y + x.z * y.z + x.w * y.w;
    }
    sc[v] = acc * 0.08838834764831843f;  // 1/sqrt(128)
}

__global__ void pdist_k(float* __restrict__ out, const float* __restrict__ A,
                        const float* __restrict__ Bm, const int* __restrict__ ia,
                        const int* __restrict__ ib, int P)
{
    int p = blockIdx.x * 256 + threadIdx.x;
    if (p >= P) return;
    const float4* a = (const float4*)(A + (size_t)ia[p] * HD);
    const float4* b = (const float4*)(Bm + (size_t)ib[p] * HD);
    float acc = 0.f;
#pragma unroll
    for (int i = 0; i < 32; ++i) {
        float4 x = a[i], y = b[i];
        float d0 = x.x - y.x + 1e-6f, d1 = x.y - y.y + 1e-6f;
        float d2 = x.z - y.z + 1e-6f, d3 = x.w - y.w + 1e-6f;
        acc += d0 * d0 + d1 * d1 + d2 * d2 + d3 * d3;
    }
    out[p] = sqrtf(acc);
}

// ---------------------------------------------------------------- host

static inline unsigned gupd(size_t n) { return (unsigned)((n + 255) / 256); }
static inline unsigned gup4(size_t n) { return (unsigned)((n + 3) / 4); }

struct WArena { unsigned short* p; int Kpad; };

static void gemm3s(hipStream_t st, const float* A0, int K0, const float* A1, int K1,
                   const float* A2, int K2, WArena wa, const float* bias,
                   float* C, int M, int N, int act,
                   const float* G1 = nullptr, const float* G2 = nullptr,
                   const int* ridx1 = nullptr, int g2ridx = 0)
{
    if (M <= 24576) {
        dim3 g((M + 31) / 32, N / 128);
        gemm_mfma_t<32><<<g, 256, 0, st>>>(A0, A1, A2, K0, K1, K2, K0, K1, K2,
                                           wa.p, wa.Kpad, bias, C, M, N, act,
                                           G1, G2, ridx1, g2ridx);
    } else {
        dim3 g((M + 63) / 64, N / 128);
        gemm_mfma_t<64><<<g, 256, 0, st>>>(A0, A1, A2, K0, K1, K2, K0, K1, K2,
                                           wa.p, wa.Kpad, bias, C, M, N, act,
                                           G1, G2, ridx1, g2ridx);
    }
}
static void gemm1(hipStream_t st, const float* A, int K, WArena wa, const float* bias,
                  float* C, int M, int N, int act)
{ gemm3s(st, A, K, nullptr, 0, nullptr, 0, wa, bias, C, M, N, act); }

extern "C" void kernel_launch(void* const* d_in, const int* in_sizes, int n_in,
                              void* d_out, int out_size, void* d_ws, size_t ws_size,
                              hipStream_t stream)
{
    (void)n_in; (void)out_size;
    const float* vert_x  = (const float*)d_in[0];
    const float* site_x  = (const float*)d_in[1];
    const float* masf_x  = (const float*)d_in[2];
    const float* prot_ea = (const float*)d_in[3];
    const float* prom_ea = (const float*)d_in[4];
    const int* vert_src = (const int*)d_in[5];
    const int* vert_dst = (const int*)d_in[6];
    const int* vbatch   = (const int*)d_in[7];
    const int* comp_src = (const int*)d_in[8];
    const int* comp_dst = (const int*)d_in[9];
    const int* site_src = (const int*)d_in[10];
    const int* site_dst = (const int*)d_in[11];
    const int* masf_src = (const int*)d_in[12];
    const int* masf_dst = (const int*)d_in[13];
    const int* prot_src = (const int*)d_in[14];
    const int* prot_dst = (const int*)d_in[15];
    const int* prom_src = (const int*)d_in[16];
    const int* prom_dst = (const int*)d_in[17];
    const int* anch_src = (const int*)d_in[18];
    const int* anch_dst = (const int*)d_in[19];
    const int* ag_a = (const int*)d_in[20];
    const int* ag_g = (const int*)d_in[21];
    const int* aa0  = (const int*)d_in[22];
    const int* aa1  = (const int*)d_in[23];
    const int* gg0  = (const int*)d_in[24];
    const int* gg1  = (const int*)d_in[25];
    const float* W_emb = (const float*)d_in[26];
    const float* b_emb = (const float*)d_in[27];
    const float* gW_main = (const float*)d_in[28];
    const float* gW_s2m  = (const float*)d_in[29];
    const float* gW_gm   = (const float*)d_in[30];
    const float* gb_gm   = (const float*)d_in[31];
    const float* gW_q    = (const float*)d_in[32];
    const float* gW_k    = (const float*)d_in[33];
    const float* gW_mrg  = (const float*)d_in[34];
    const float* gW_gs   = (const float*)d_in[35];
    const float* gb_gs   = (const float*)d_in[36];
    const float* gm_Wih = (const float*)d_in[37];
    const float* gm_Whh = (const float*)d_in[38];
    const float* gm_bih = (const float*)d_in[39];
    const float* gm_bhh = (const float*)d_in[40];
    const float* gs_Wih = (const float*)d_in[41];
    const float* gs_Whh = (const float*)d_in[42];
    const float* gs_bih = (const float*)d_in[43];
    const float* gs_bhh = (const float*)d_in[44];
    const float* W_s0 = (const float*)d_in[45];
    const float* b_s0 = (const float*)d_in[46];
    const float* W_s1 = (const float*)d_in[47];
    const float* b_s1 = (const float*)d_in[48];
    const float* W_so = (const float*)d_in[49];
    const float* b_so = (const float*)d_in[50];
    const float* W_m0 = (const float*)d_in[51];
    const float* b_m0 = (const float*)d_in[52];
    const float* W_m1 = (const float*)d_in[53];
    const float* b_m1 = (const float*)d_in[54];
    const float* W_mo = (const float*)d_in[55];
    const float* b_mo = (const float*)d_in[56];
    const float* W_a0 = (const float*)d_in[57];
    const float* b_a0 = (const float*)d_in[58];
    const float* W_a1 = (const float*)d_in[59];
    const float* b_a1 = (const float*)d_in[60];
    const float* W_ao = (const float*)d_in[61];
    const float* b_ao = (const float*)d_in[62];
    const float* W_ds = (const float*)d_in[63];
    const float* b_ds = (const float*)d_in[64];
    const float* W_dc = (const float*)d_in[65];
    const float* b_dc = (const float*)d_in[66];

    const int B = 256, NG = 4000, NA = 10000, Ns = 80000, Nm = 80000;
    const int Nv = in_sizes[7];
    const int FV = in_sizes[0] / Nv;
    const int Fs = in_sizes[1] / Ns;
    const int Fm = in_sizes[2] / Nm;
    const int Ev = in_sizes[5], Ec = in_sizes[8], Es = in_sizes[10], Em = in_sizes[12];
    const int Ep = in_sizes[14], Ea = in_sizes[18];
    const int Pag = in_sizes[20], Paa = in_sizes[22], Pgg = in_sizes[24];
    const int D = in_sizes[28] / (HD * HD);

    // ---- workspace layout (floats) --------------------------------------
    float* ws = (float*)d_ws;
    size_t off = 0;
    auto take = [&](size_t n) { size_t o = off; off += n; return o; };
    float* vert  = ws + take((size_t)Nv * HD);
    float* supe  = ws + take((size_t)B * HD);
    float* qsup  = ws + take((size_t)B * HD);
    float* usup  = ws + take((size_t)B * HD);
    float* pool  = ws + take((size_t)B * HD);
    float* msup  = ws + take((size_t)B * HD);
    float* zsup  = ws + take((size_t)B * HD);
    float* gis   = ws + take((size_t)B * 3 * HD);
    float* ghs   = ws + take((size_t)B * 3 * HD);
    float* tsml  = ws + take((size_t)B * HD);
    float* grp   = ws + take((size_t)NG * HD);
    float* site_o = ws + take((size_t)Ns * HD);
    float* masf_o = ws + take((size_t)Nm * HD);
    float* anch  = ws + take((size_t)NA * 2 * HD);
    float* ah1   = ws + take((size_t)NA * HD);
    float* ah2   = ws + take((size_t)NA * HD);
    float* axw   = ws + take((size_t)NA * HD);
    float* aout  = ws + take((size_t)NA * HD);
    float* pa    = ws + take((size_t)NA * HD);
    float* pg    = ws + take((size_t)NG * HD);
    float* score = ws + take((size_t)Nv);
    const size_t NvH = (size_t)Nv * HD, NsH = (size_t)Ns * HD;
    float* T = ws + take(3 * NsH);   // shared temp region

    // ---- CSR arrays (ints), concatenated layout --------------------------
    const int nN[8] = {Nv, NG, Ns, Nm, NA, NA, NA, B};
    const int nE[8] = {Ev, Ec, Es, Em, Ep, Ep, Ea, Nv};
    const int* dsts[8] = {vert_dst, comp_dst, site_dst, masf_dst,
                          prot_dst, prom_dst, anch_dst, vbatch};
    int baseN[9], baseE[9];
    baseN[0] = 0; baseE[0] = 0;
    for (int g = 0; g < 8; ++g) { baseN[g + 1] = baseN[g] + nN[g]; baseE[g + 1] = baseE[g] + nE[g]; }
    const int totN = baseN[8], totE = baseE[8];

    int* ib = (int*)(ws + off);
    size_t ioff = 0;
    auto taki = [&](size_t n) { size_t o = ioff; ioff += n; return o; };
    int* cnt_all = ib + taki((size_t)totN);
    int* rp_all  = ib + taki((size_t)totN + 1);
    int* cur_all = ib + taki((size_t)totN);
    int* ei_all  = ib + taki((size_t)totE);
    int* bsum    = ib + taki((size_t)((totN + SCB - 1) / SCB) + 1);
    ioff = (ioff + 7) & ~(size_t)7;   // 16B-align the bf16 arena

    // ---- bf16 weight arenas ----------------------------------------------
    unsigned short* warena = (unsigned short*)(ib + ioff);
    size_t woff = 0;
    WBatch wb; int nW = 0; long maxWTot = 0;
    auto reg = [&](const float* src, int K, int N, int tr) {
        int Kpad = (K + 31) & ~31;
        unsigned short* dst = warena + woff;
        woff += (size_t)N * Kpad;
        long tot = (long)N * Kpad; if (tot > maxWTot) maxWTot = tot;
        wb.d[nW].src = src; wb.d[nW].dst = dst; wb.d[nW].K = K;
        wb.d[nW].N = N; wb.d[nW].Kpad = Kpad; wb.d[nW].tr = tr;
        ++nW;
        WArena a; a.p = dst; a.Kpad = Kpad; return a;
    };
    WArena wa_emb = reg(W_emb, FV, HD, 1);
    WArena wa_main[2], wa_s2m[2], wa_gm[2], wa_q[2], wa_kT[2], wa_mrg[2], wa_gs[2];
    for (int t = 0; t < D && t < 2; ++t) {
        wa_main[t] = reg(gW_main + (size_t)t * HD * HD, HD, HD, 1);
        wa_s2m[t]  = reg(gW_s2m  + (size_t)t * HD * HD, HD, HD, 1);
        wa_gm[t]   = reg(gW_gm   + (size_t)t * 2 * HD * HD, 2 * HD, HD, 1);
        wa_q[t]    = reg(gW_q    + (size_t)t * HD * HD, HD, HD, 1);
        wa_kT[t]   = reg(gW_k    + (size_t)t * HD * HD, HD, HD, 0);  // u = q @ Wk^T
        wa_mrg[t]  = reg(gW_mrg  + (size_t)t * HD * HD, HD, HD, 1);
        wa_gs[t]   = reg(gW_gs   + (size_t)t * 2 * HD * HD, 2 * HD, HD, 1);
    }
    WArena wa_mih = reg(gm_Wih, HD, 3 * HD, 0);   // GRU: x@Wih.T -> WT = Wih as-is
    WArena wa_mhh = reg(gm_Whh, HD, 3 * HD, 0);
    WArena wa_sih = reg(gs_Wih, HD, 3 * HD, 0);
    WArena wa_shh = reg(gs_Whh, HD, 3 * HD, 0);
    WArena wa_s0 = reg(W_s0, Fs, HD, 1);
    WArena wa_s1 = reg(W_s1, HD, HD, 1);
    WArena wa_so = reg(W_so, Fs + 2 * HD, HD, 1);
    WArena wa_m0 = reg(W_m0, Fm, HD, 1);
    WArena wa_m1 = reg(W_m1, HD, HD, 1);
    WArena wa_mo = reg(W_mo, Fm + 2 * HD, HD, 1);
    WArena wa_a0 = reg(W_a0, 2 * HD, HD, 1);
    WArena wa_a1 = reg(W_a1, HD, HD, 1);
    WArena wa_ao = reg(W_ao, 4 * HD, HD, 1);
    WArena wa_ds = reg(W_ds, HD, HD, 1);
    WArena wa_dc = reg(W_dc, HD, HD, 1);

    if (ws_size < off * sizeof(float) + ioff * sizeof(int) + woff * sizeof(unsigned short))
        return;

    {
        dim3 g((unsigned)((maxWTot + 255) / 256), nW);
        hipLaunchKernelGGL(convert_weights, g, dim3(256), 0, stream, wb);
    }

    // ---- CSR build --------------------------------------------------------
    hipMemsetAsync(cnt_all, 0, (size_t)totN * sizeof(int), stream);
    for (int g = 0; g < 8; ++g)
        hist_k<<<gupd((size_t)nE[g]), 256, 0, stream>>>(cnt_all + baseN[g], dsts[g], nE[g]);
    const int nScanBlocks = (totN + SCB - 1) / SCB;
    scan_sums<<<nScanBlocks, 256, 0, stream>>>(cnt_all, totN, bsum);
    scan_bsum<<<1, 64, 0, stream>>>(bsum, nScanBlocks);
    scan_write<<<nScanBlocks, 256, 0, stream>>>(cnt_all, totN, bsum, rp_all);
    hipMemcpyAsync(cur_all, rp_all, (size_t)totN * sizeof(int), hipMemcpyDeviceToDevice, stream);
    for (int g = 0; g < 8; ++g)
        fill_k<<<gupd((size_t)nE[g]), 256, 0, stream>>>(ei_all, cur_all + baseN[g], dsts[g], nE[g]);

    const int* rp_v = rp_all + baseN[0];
    const int* rp_c = rp_all + baseN[1];
    const int* rp_s = rp_all + baseN[2];
    const int* rp_m = rp_all + baseN[3];
    const int* rp_p = rp_all + baseN[4];
    const int* rp_q = rp_all + baseN[5];
    const int* rp_a = rp_all + baseN[6];
    const int* rp_b = rp_all + baseN[7];
    const int* ei = ei_all;

    // ---- embedding + super-node init ------------------------------------
    gemm1(stream, vert_x, FV, wa_emb, b_emb, vert, Nv, HD, 1);
    seg_gather<<<gup4(B), 256, 0, stream>>>(supe, vert, rp_b, ei, nullptr, nullptr,
                                            nullptr, B, HD, 0, 0, 0);

    // ---- GWM iterations ---------------------------------------------------
    float* Ta = T;            float* Tb = T + NvH;
    float* Td = T + 3 * NvH;  float* Te = T + 4 * NvH; float* Tf = T + 7 * NvH;
    for (int t = 0; t < D; ++t) {
        const float* bgm = gb_gm + (size_t)t * HD;
        const float* bgs = gb_gs + (size_t)t * HD;

        gemm1(stream, vert, HD, wa_main[t], nullptr, Ta, Nv, HD, 0);
        seg_gather<<<gup4((size_t)Nv), 256, 0, stream>>>(Tb, Ta, rp_v, ei, vert_src,
                                                         nullptr, nullptr, Nv, HD, 0, 1, 0);
        gemm1(stream, supe, HD, wa_s2m[t], nullptr, tsml, B, HD, 1);
        // gate gemm with fused trans gather: A1/G2 rows = tsml[vbatch[row]]
        gemm3s(stream, Tb, HD, tsml, HD, nullptr, 0, wa_gm[t], bgm, Td, Nv, HD, 3,
               Tb, tsml, vbatch, 1);
        gemm1(stream, Td, HD, wa_mih, gm_bih, Te, Nv, 3 * HD, 0);
        gemm1(stream, vert, HD, wa_mhh, gm_bhh, Tf, Nv, 3 * HD, 0);
        gru_gate<<<gupd(NvH), 256, 0, stream>>>(vert, Te, Tf, Nv);
        // attention: u_b = (supe@Wq) @ Wk^T  (tiny), score = vert . u[batch]
        gemm1(stream, supe, HD, wa_q[t], nullptr, qsup, B, HD, 0);
        gemm1(stream, qsup, HD, wa_kT[t], nullptr, usup, B, HD, 0);
        dot_score<<<gupd((size_t)Nv), 256, 0, stream>>>(score, vert, usup, vbatch, Nv);
        seg_softmax_csr<<<gup4(B), 256, 0, stream>>>(score, rp_b, ei, B);
        seg_gather<<<gup4(B), 256, 0, stream>>>(pool, vert, rp_b, ei, nullptr, score,
                                                nullptr, B, HD, 0, 0, 1);
        gemm1(stream, pool, HD, wa_mrg[t], nullptr, msup, B, HD, 1);
        gemm3s(stream, msup, HD, supe, HD, nullptr, 0, wa_gs[t], bgs, zsup, B, HD, 3,
               msup, supe, nullptr, 0);
        gemm1(stream, zsup, HD, wa_sih, gs_bih, gis, B, 3 * HD, 0);
        gemm1(stream, supe, HD, wa_shh, gs_bhh, ghs, B, 3 * HD, 0);
        gru_gate<<<gupd((size_t)B * HD), 256, 0, stream>>>(supe, gis, ghs, B);
    }

    // ---- Group module ------------------------------------------------------
    seg_gather<<<gup4((size_t)NG), 256, 0, stream>>>(grp, vert, rp_c, ei, comp_src,
                                                     nullptr, nullptr, NG, HD, 0, 0, 2);

    // ---- site conv stack ---------------------------------------------------
    float* T1 = T; float* T2 = T + NsH; float* T3 = T + 2 * NsH;
    gemm1(stream, site_x, Fs, wa_s0, nullptr, T1, Ns, HD, 0);
    seg_gather<<<gup4((size_t)Ns), 256, 0, stream>>>(T2, T1, rp_s, ei, site_src,
                                                     nullptr, b_s0, Ns, HD, 0, 1, 0);
    gemm1(stream, T2, HD, wa_s1, nullptr, T1, Ns, HD, 0);
    seg_gather<<<gup4((size_t)Ns), 256, 0, stream>>>(T3, T1, rp_s, ei, site_src,
                                                     nullptr, b_s1, Ns, HD, 0, 1, 0);
    gemm3s(stream, site_x, Fs, T2, HD, T3, HD, wa_so, b_so, site_o, Ns, HD, 1);

    // ---- masf conv stack ---------------------------------------------------
    gemm1(stream, masf_x, Fm, wa_m0, nullptr, T1, Nm, HD, 0);
    seg_gather<<<gup4((size_t)Nm), 256, 0, stream>>>(T2, T1, rp_m, ei, masf_src,
                                                     nullptr, b_m0, Nm, HD, 0, 1, 0);
    gemm1(stream, T2, HD, wa_m1, nullptr, T1, Nm, HD, 0);
    seg_gather<<<gup4((size_t)Nm), 256, 0, stream>>>(T3, T1, rp_m, ei, masf_src,
                                                     nullptr, b_m1, Nm, HD, 0, 1, 0);
    gemm3s(stream, masf_x, Fm, T2, HD, T3, HD, wa_mo, b_mo, masf_o, Nm, HD, 1);

    // ---- anchor pooling ----------------------------------------------------
    seg_gather<<<gup4((size_t)NA), 256, 0, stream>>>(anch, site_o, rp_p, ei, prot_src,
                                                     prot_ea, nullptr, NA, 2 * HD, 0, 0, 3);
    seg_gather<<<gup4((size_t)NA), 256, 0, stream>>>(anch, masf_o, rp_q, ei, prom_src,
                                                     prom_ea, nullptr, NA, 2 * HD, HD, 0, 3);

    // ---- anchor conv stack -------------------------------------------------
    gemm1(stream, anch, 2 * HD, wa_a0, nullptr, axw, NA, HD, 0);
    seg_gather<<<gup4((size_t)NA), 256, 0, stream>>>(ah1, axw, rp_a, ei, anch_src,
                                                     nullptr, b_a0, NA, HD, 0, 1, 0);
    gemm1(stream, ah1, HD, wa_a1, nullptr, axw, NA, HD, 0);
    seg_gather<<<gup4((size_t)NA), 256, 0, stream>>>(ah2, axw, rp_a, ei, anch_src,
                                                     nullptr, b_a1, NA, HD, 0, 1, 0);
    gemm3s(stream, anch, 2 * HD, ah1, HD, ah2, HD, wa_ao, b_ao, aout, NA, HD, 1);

    // ---- distance heads ----------------------------------------------------
    gemm1(stream, aout, HD, wa_ds, b_ds, pa, NA, HD, 1);
    gemm1(stream, grp, HD, wa_dc, b_dc, pg, NG, HD, 1);
    float* outp = (float*)d_out;
    pdist_k<<<gupd((size_t)Pag), 256, 0, stream>>>(outp, pa, pg, ag_a, ag_g, Pag);
    pdist_k<<<gupd((size_t)Paa), 256, 0, stream>>>(outp + Pag, pa, pa, aa0, aa1, Paa);
    pdist_k<<<gupd((size_t)Pgg), 256, 0, stream>>>(outp + Pag + Paa, pg, pg, gg0, gg1, Pgg);
}

// Round 14
// 1260.726 us; speedup vs baseline: 1.1190x; 1.0063x over previous
//
#include <hip/hip_runtime.h>
#include <math.h>

#define HD 128  // hidden dim

typedef __bf16 bf16x8 __attribute__((ext_vector_type(8)));
typedef unsigned short u16x8 __attribute__((ext_vector_type(8)));
typedef float f32x4 __attribute__((ext_vector_type(4)));

__device__ __forceinline__ unsigned short f2bf(float f) {
    unsigned u = __float_as_uint(f);
    unsigned r = u + 0x7FFFu + ((u >> 16) & 1u);   // RTN-even
    return (unsigned short)(r >> 16);
}

// ---------------------------------------------------------------- weight convert
#define MAXW 32
struct WDesc { const float* src; unsigned short* dst; int K, N, Kpad, tr; };
struct WBatch { WDesc d[MAXW]; };

__global__ void convert_weights(WBatch wb)
{
    WDesc d = wb.d[blockIdx.y];
    long total = (long)d.N * d.Kpad;
    long i = (long)blockIdx.x * 256 + threadIdx.x;
    if (i >= total) return;
    int n = (int)(i / d.Kpad), k = (int)(i % d.Kpad);
    float v = 0.f;
    if (k < d.K) v = d.tr ? d.src[(size_t)k * d.N + n] : d.src[(size_t)n * d.K + k];
    d.dst[i] = f2bf(v);
}

// ---------------------------------------------------------------- MFMA GEMM
// C[M,N] = act( [A0|A1|A2] @ W + bias ), W as bf16 WT[N][Kpad].
// act: 0 none, 1 lrelu, 2 sigmoid, 3 gate: C = z*G1 + (1-z)*G2, z=sigmoid(v).
// ridx1: row-index for segment A1 (and G2 when g2ridx) - fuses gathers.
// BMT = 64 (M-large) or 32 (M-small: doubles grid, 6 blocks/CU - GWM gemms
// were 1.2 blocks/CU at BM=64). Depth-1 register prefetch (proven best;
// deeper pipelines cost occupancy > latency gain). One raw s_barrier/tile,
// only lgkmcnt drained. C/D: col=lane&15, row=(lane>>4)*4+reg [m89-verified].
template<int BMT>
__global__ __launch_bounds__(256)
void gemm_mfma_t(const float* __restrict__ A0, const float* __restrict__ A1,
                 const float* __restrict__ A2, int K0, int K1, int K2,
                 int lda0, int lda1, int lda2,
                 const unsigned short* __restrict__ WT, int Kpad,
                 const float* __restrict__ bias, float* __restrict__ C,
                 int M, int N, int act,
                 const float* __restrict__ G1, const float* __restrict__ G2,
                 const int* __restrict__ ridx1, int g2ridx)
{
    constexpr int NRF = BMT / 16;           // row fragments per wave
    __shared__ __align__(16) unsigned short sA[2][BMT][40];
    __shared__ __align__(16) unsigned short sW[2][128][40];

    const int tid = threadIdx.x;
    const int lane = tid & 63, w = tid >> 6;
    const int mBase = blockIdx.x * BMT;
    const int nBase = blockIdx.y * 128;
    const int Ktot = K0 + K1 + K2;
    const int colb = w * 32;
    const int c16 = lane & 15, g = lane >> 4;

    f32x4 acc[NRF][2];
#pragma unroll
    for (int i = 0; i < NRF; ++i)
#pragma unroll
        for (int j = 0; j < 2; ++j) acc[i][j] = (f32x4){0.f, 0.f, 0.f, 0.f};

    const int kTiles = (Ktot + 31) / 32;
    const bool aLoader = (BMT == 64) || (tid < 128);   // BMT*32 elems, 8/thread

    auto loadTile = [&](int kt, float f[8], u16x8& h0, u16x8& h1) {
        const int k0g = kt * 32;
        const float* Ab; int lda, kloc, segK; const int* ri = nullptr;
        if (k0g < K0)           { Ab = A0; lda = lda0; kloc = k0g;           segK = K0; }
        else if (k0g < K0 + K1) { Ab = A1; lda = lda1; kloc = k0g - K0;      segK = K1; ri = ridx1; }
        else                    { Ab = A2; lda = lda2; kloc = k0g - K0 - K1; segK = K2; }
        if (aLoader) {
            int row = tid >> 2, kq = (tid & 3) * 8;
            int gr = mBase + row;
            int ar = (ri && gr < M) ? ri[gr] : gr;
            if (gr < M && ((lda & 3) == 0) && (kloc + kq + 8 <= segK)) {
                const float* ap = Ab + (size_t)ar * lda + kloc + kq;
                float4 v0 = *(const float4*)ap, v1 = *(const float4*)(ap + 4);
                f[0] = v0.x; f[1] = v0.y; f[2] = v0.z; f[3] = v0.w;
                f[4] = v1.x; f[5] = v1.y; f[6] = v1.z; f[7] = v1.w;
            } else {
#pragma unroll
                for (int i = 0; i < 8; ++i) {
                    int kk = kloc + kq + i;
                    f[i] = (gr < M && kk < segK) ? Ab[(size_t)ar * lda + kk] : 0.f;
                }
            }
        }
        int col = tid >> 1, kh = (tid & 1) * 16;
        const unsigned short* wp = WT + (size_t)(nBase + col) * Kpad + k0g + kh;
        h0 = *(const u16x8*)wp;
        h1 = *(const u16x8*)(wp + 8);
    };
    auto stageWrite = [&](int buf, const float f[8], u16x8 h0, u16x8 h1) {
        if (aLoader) {
            int row = tid >> 2, kq = (tid & 3) * 8;
            u16x8 h;
#pragma unroll
            for (int i = 0; i < 8; ++i) h[i] = f2bf(f[i]);
            *(u16x8*)&sA[buf][row][kq] = h;
        }
        int col = tid >> 1, kh = (tid & 1) * 16;
        *(u16x8*)&sW[buf][col][kh] = h0;
        *(u16x8*)&sW[buf][col][kh + 8] = h1;
    };
    auto compute = [&](int buf) {
        bf16x8 bfr0 = __builtin_bit_cast(bf16x8, *(const u16x8*)&sW[buf][colb + c16][g * 8]);
        bf16x8 bfr1 = __builtin_bit_cast(bf16x8, *(const u16x8*)&sW[buf][colb + 16 + c16][g * 8]);
#pragma unroll
        for (int rf = 0; rf < NRF; ++rf) {
            bf16x8 af = __builtin_bit_cast(bf16x8, *(const u16x8*)&sA[buf][rf * 16 + c16][g * 8]);
            acc[rf][0] = __builtin_amdgcn_mfma_f32_16x16x32_bf16(af, bfr0, acc[rf][0], 0, 0, 0);
            acc[rf][1] = __builtin_amdgcn_mfma_f32_16x16x32_bf16(af, bfr1, acc[rf][1], 0, 0, 0);
        }
    };

    // prologue: stage tile 0, prefetch tile 1
    float fN[8]; u16x8 hN0, hN1;
    {
        float fC[8]; u16x8 hC0, hC1;
        loadTile(0, fC, hC0, hC1);
        stageWrite(0, fC, hC0, hC1);
        if (kTiles > 1) loadTile(1, fN, hN0, hN1);
    }
    asm volatile("s_waitcnt lgkmcnt(0)" ::: "memory");
    __builtin_amdgcn_s_barrier();

    int cur = 0;
#pragma unroll 2
    for (int kt = 0; kt < kTiles; ++kt) {
        float fP[8]; u16x8 hP0, hP1;
        const bool pf = (kt + 2 < kTiles);
        if (pf) loadTile(kt + 2, fP, hP0, hP1);     // issue early: hides under MFMA+stage
        compute(cur);
        if (kt + 1 < kTiles) stageWrite(cur ^ 1, fN, hN0, hN1);
        asm volatile("s_waitcnt lgkmcnt(0)" ::: "memory");
        __builtin_amdgcn_s_barrier();
        if (pf) {
#pragma unroll
            for (int i = 0; i < 8; ++i) fN[i] = fP[i];
            hN0 = hP0; hN1 = hP1;
        }
        cur ^= 1;
    }

    // ---- epilogue
#pragma unroll
    for (int cf = 0; cf < 2; ++cf) {
        int col = nBase + colb + cf * 16 + c16;
        float bb = bias ? bias[col] : 0.f;
#pragma unroll
        for (int rf = 0; rf < NRF; ++rf) {
            int r0 = mBase + rf * 16 + g * 4;
#pragma unroll
            for (int r = 0; r < 4; ++r) {
                int gr = r0 + r;
                if (gr >= M) continue;
                size_t o = (size_t)gr * N + col;
                float v = acc[rf][cf][r] + bb;
                if (act == 1) v = v > 0.f ? v : 0.1f * v;
                else if (act == 2) v = 1.f / (1.f + expf(-v));
                else if (act == 3) {
                    float z = 1.f / (1.f + expf(-v));
                    size_t o2 = g2ridx ? ((size_t)ridx1[gr] * N + col) : o;
                    v = z * G1[o] + (1.f - z) * G2[o2];
                }
                C[o] = v;
            }
        }
    }
}

// ---------------------------------------------------------------- CSR build
__global__ void hist_k(int* __restrict__ cnt, const int* __restrict__ dst, int E)
{
    int i = blockIdx.x * 256 + threadIdx.x;
    if (i < E) atomicAdd(&cnt[dst[i]], 1);
}

#define SCB 4096

__global__ __launch_bounds__(256)
void scan_sums(const int* __restrict__ cnt, int n, int* __restrict__ bsum)
{
    __shared__ int red[256];
    int t = threadIdx.x;
    int base = blockIdx.x * SCB + t * 16;
    int s = 0;
#pragma unroll
    for (int i = 0; i < 16; ++i) { int idx = base + i; if (idx < n) s += cnt[idx]; }
    red[t] = s; __syncthreads();
    for (int st = 128; st > 0; st >>= 1) {
        if (t < st) red[t] += red[t + st];
        __syncthreads();
    }
    if (t == 0) bsum[blockIdx.x] = red[0];
}

__global__ void scan_bsum(int* __restrict__ bsum, int nb)
{
    if (threadIdx.x == 0) {
        int run = 0;
        for (int i = 0; i < nb; ++i) { int v = bsum[i]; bsum[i] = run; run += v; }
    }
}

__global__ __launch_bounds__(256)
void scan_write(const int* __restrict__ cnt, int n, const int* __restrict__ bsum,
                int* __restrict__ rp)
{
    __shared__ int a0[256], a1[256];
    int t = threadIdx.x;
    int base = blockIdx.x * SCB + t * 16;
    int v[16]; int s = 0;
#pragma unroll
    for (int i = 0; i < 16; ++i) { int idx = base + i; v[i] = (idx < n) ? cnt[idx] : 0; s += v[i]; }
    a0[t] = s; __syncthreads();
    int* cur = a0; int* nxt = a1;
    for (int st = 1; st < 256; st <<= 1) {
        int val = cur[t] + ((t >= st) ? cur[t - st] : 0);
        nxt[t] = val; __syncthreads();
        int* tmp = cur; cur = nxt; nxt = tmp;
    }
    int run = bsum[blockIdx.x] + (t > 0 ? cur[t - 1] : 0);
#pragma unroll
    for (int i = 0; i < 16; ++i) {
        int idx = base + i;
        if (idx < n) {
            rp[idx] = run; run += v[i];
            if (idx == n - 1) rp[n] = run;
        }
    }
}

__global__ void fill_k(int* __restrict__ eidx, int* __restrict__ cursor,
                       const int* __restrict__ dst, int E)
{
    int i = blockIdx.x * 256 + threadIdx.x;
    if (i < E) eidx[atomicAdd(&cursor[dst[i]], 1)] = i;
}

// ---------------------------------------------------------------- CSR gather
// One wave per destination row; lane covers 2 feats (float2).
// mode 0: w=1   1: w=wattr[e]   2: w=1/deg   3: w=softmax(6-wattr)[e]
__global__ __launch_bounds__(256)
void seg_gather(float* __restrict__ out, const float* __restrict__ X,
                const int* __restrict__ rowptr, const int* __restrict__ eidx,
                const int* __restrict__ src, const float* __restrict__ wattr,
                const float* __restrict__ bias, int n, int ostride, int ooff,
                int act, int mode)
{
    int d = blockIdx.x * 4 + (threadIdx.x >> 6);
    if (d >= n) return;
    int lane = threadIdx.x & 63;
    int lo = rowptr[d], hi = rowptr[d + 1];
    float w0 = 1.f, mx = 0.f, iden = 0.f;
    if (mode == 2) w0 = (hi > lo) ? 1.f / (float)(hi - lo) : 0.f;
    if (mode == 3) {
        float mxl = -1e30f;
        for (int base = lo; base < hi; base += 64) {
            int i = base + lane;
            if (i < hi) mxl = fmaxf(mxl, 6.f - wattr[eidx[i]]);
        }
#pragma unroll
        for (int o = 32; o; o >>= 1) mxl = fmaxf(mxl, __shfl_xor(mxl, o));
        mx = mxl;
        float dl = 0.f;
        for (int base = lo; base < hi; base += 64) {
            int i = base + lane;
            if (i < hi) dl += expf(6.f - wattr[eidx[i]] - mx);
        }
#pragma unroll
        for (int o = 32; o; o >>= 1) dl += __shfl_xor(dl, o);
        iden = 1.f / dl;
    }

    float ax = 0.f, ay = 0.f;
    int i = lo;
    for (; i + 4 <= hi; i += 4) {
        int e0 = eidx[i], e1 = eidx[i + 1], e2 = eidx[i + 2], e3 = eidx[i + 3];
        int s0 = src ? src[e0] : e0, s1 = src ? src[e1] : e1;
        int s2 = src ? src[e2] : e2, s3 = src ? src[e3] : e3;
        float w0v, w1v, w2v, w3v;
        if (mode == 0) { w0v = w1v = w2v = w3v = 1.f; }
        else if (mode == 1) { w0v = wattr[e0]; w1v = wattr[e1]; w2v = wattr[e2]; w3v = wattr[e3]; }
        else if (mode == 2) { w0v = w1v = w2v = w3v = w0; }
        else {
            w0v = expf(6.f - wattr[e0] - mx) * iden;
            w1v = expf(6.f - wattr[e1] - mx) * iden;
            w2v = expf(6.f - wattr[e2] - mx) * iden;
            w3v = expf(6.f - wattr[e3] - mx) * iden;
        }
        float2 v0 = *(const float2*)(X + (size_t)s0 * HD + 2 * lane);
        float2 v1 = *(const float2*)(X + (size_t)s1 * HD + 2 * lane);
        float2 v2 = *(const float2*)(X + (size_t)s2 * HD + 2 * lane);
        float2 v3 = *(const float2*)(X + (size_t)s3 * HD + 2 * lane);
        ax += w0v * v0.x + w1v * v1.x + w2v * v2.x + w3v * v3.x;
        ay += w0v * v0.y + w1v * v1.y + w2v * v2.y + w3v * v3.y;
    }
    for (; i < hi; ++i) {
        int e = eidx[i];
        int s = src ? src[e] : e;
        float w;
        if (mode == 0) w = 1.f;
        else if (mode == 1) w = wattr[e];
        else if (mode == 2) w = w0;
        else w = expf(6.f - wattr[e] - mx) * iden;
        float2 v = *(const float2*)(X + (size_t)s * HD + 2 * lane);
        ax += w * v.x; ay += w * v.y;
    }
    if (bias) { float2 b = *(const float2*)(bias + 2 * lane); ax += b.x; ay += b.y; }
    if (act == 1) { ax = ax > 0.f ? ax : 0.1f * ax; ay = ay > 0.f ? ay : 0.1f * ay; }
    *(float2*)(out + (size_t)d * ostride + ooff + 2 * lane) = make_float2(ax, ay);
}

// ---------------------------------------------------------------- fused segment softmax
__global__ __launch_bounds__(256)
void seg_softmax_csr(float* __restrict__ sc, const int* __restrict__ rowptr,
                     const int* __restrict__ eidx, int n)
{
    int d = blockIdx.x * 4 + (threadIdx.x >> 6);
    if (d >= n) return;
    int lane = threadIdx.x & 63;
    int lo = rowptr[d], hi = rowptr[d + 1];
    float mxl = -1e30f;
    for (int i = lo + lane; i < hi; i += 64) mxl = fmaxf(mxl, sc[eidx[i]]);
#pragma unroll
    for (int o = 32; o; o >>= 1) mxl = fmaxf(mxl, __shfl_xor(mxl, o));
    float dl = 0.f;
    for (int i = lo + lane; i < hi; i += 64) dl += expf(sc[eidx[i]] - mxl);
#pragma unroll
    for (int o = 32; o; o >>= 1) dl += __shfl_xor(dl, o);
    float iden = 1.f / dl;
    for (int i = lo + lane; i < hi; i += 64) {
        int v = eidx[i];
        sc[v] = expf(sc[v] - mxl) * iden;
    }
}

// ---------------------------------------------------------------- misc kernels
__global__ void gru_gate(float* __restrict__ h, const float* __restrict__ gi,
                         const float* __restrict__ gh, int M)
{
    long i = (long)blockIdx.x * 256 + threadIdx.x;
    if (i >= (long)M * HD) return;
    int row = (int)(i >> 7), f = (int)(i & 127);
    size_t o = (size_t)row * 384 + f;
    float r = 1.f / (1.f + expf(-(gi[o] + gh[o])));
    float z = 1.f / (1.f + expf(-(gi[o + 128] + gh[o + 128])));
    float n = tanhf(gi[o + 256] + r * gh[o + 256]);
    h[i] = (1.f - z) * n + z * h[i];
}

// score[v] = dot(vert[v], u[batch[v]]) / sqrt(128)   (u = q @ Wk^T)
__global__ void dot_score(float* __restrict__ sc, const float* __restrict__ vert,
                          const float* __restrict__ u, const int* __restrict__ batch, int n)
{
    int v = blockIdx.x * 256 + threadIdx.x;
    if (v >= n) return;
    const float4* a = (const float4*)(vert + (size_t)v * HD);
    const float4* q = (const float4*)(u + (size_t)batch[v] * HD);
    float acc = 0.f;
#pragma unroll
    for (int i = 0; i < 32; ++i) {
        float4 x = a[i], y = q[i];
        acc += x.x * y.x + x.y * y.y + x.z * y.z + x.w * y.w;
    }
    sc[v] = acc * 0.08838834764831843f;  // 1/sqrt(128)
}

__global__ void pdist_k(float* __restrict__ out, const float* __restrict__ A,
                        const float* __restrict__ Bm, const int* __restrict__ ia,
                        const int* __restrict__ ib, int P)
{
    int p = blockIdx.x * 256 + threadIdx.x;
    if (p >= P) return;
    const float4* a = (const float4*)(A + (size_t)ia[p] * HD);
    const float4* b = (const float4*)(Bm + (size_t)ib[p] * HD);
    float acc = 0.f;
#pragma unroll
    for (int i = 0; i < 32; ++i) {
        float4 x = a[i], y = b[i];
        float d0 = x.x - y.x + 1e-6f, d1 = x.y - y.y + 1e-6f;
        float d2 = x.z - y.z + 1e-6f, d3 = x.w - y.w + 1e-6f;
        acc += d0 * d0 + d1 * d1 + d2 * d2 + d3 * d3;
    }
    out[p] = sqrtf(acc);
}

// ---------------------------------------------------------------- host

static inline unsigned gupd(size_t n) { return (unsigned)((n + 255) / 256); }
static inline unsigned gup4(size_t n) { return (unsigned)((n + 3) / 4); }

struct WArena { unsigned short* p; int Kpad; };

static void gemm3s(hipStream_t st, const float* A0, int K0, const float* A1, int K1,
                   const float* A2, int K2, WArena wa, const float* bias,
                   float* C, int M, int N, int act,
                   const float* G1 = nullptr, const float* G2 = nullptr,
                   const int* ridx1 = nullptr, int g2ridx = 0)
{
    if (M <= 24576) {
        dim3 g((M + 31) / 32, N / 128);
        gemm_mfma_t<32><<<g, 256, 0, st>>>(A0, A1, A2, K0, K1, K2, K0, K1, K2,
                                           wa.p, wa.Kpad, bias, C, M, N, act,
                                           G1, G2, ridx1, g2ridx);
    } else {
        dim3 g((M + 63) / 64, N / 128);
        gemm_mfma_t<64><<<g, 256, 0, st>>>(A0, A1, A2, K0, K1, K2, K0, K1, K2,
                                           wa.p, wa.Kpad, bias, C, M, N, act,
                                           G1, G2, ridx1, g2ridx);
    }
}
static void gemm1(hipStream_t st, const float* A, int K, WArena wa, const float* bias,
                  float* C, int M, int N, int act)
{ gemm3s(st, A, K, nullptr, 0, nullptr, 0, wa, bias, C, M, N, act); }

extern "C" void kernel_launch(void* const* d_in, const int* in_sizes, int n_in,
                              void* d_out, int out_size, void* d_ws, size_t ws_size,
                              hipStream_t stream)
{
    (void)n_in; (void)out_size;
    const float* vert_x  = (const float*)d_in[0];
    const float* site_x  = (const float*)d_in[1];
    const float* masf_x  = (const float*)d_in[2];
    const float* prot_ea = (const float*)d_in[3];
    const float* prom_ea = (const float*)d_in[4];
    const int* vert_src = (const int*)d_in[5];
    const int* vert_dst = (const int*)d_in[6];
    const int* vbatch   = (const int*)d_in[7];
    const int* comp_src = (const int*)d_in[8];
    const int* comp_dst = (const int*)d_in[9];
    const int* site_src = (const int*)d_in[10];
    const int* site_dst = (const int*)d_in[11];
    const int* masf_src = (const int*)d_in[12];
    const int* masf_dst = (const int*)d_in[13];
    const int* prot_src = (const int*)d_in[14];
    const int* prot_dst = (const int*)d_in[15];
    const int* prom_src = (const int*)d_in[16];
    const int* prom_dst = (const int*)d_in[17];
    const int* anch_src = (const int*)d_in[18];
    const int* anch_dst = (const int*)d_in[19];
    const int* ag_a = (const int*)d_in[20];
    const int* ag_g = (const int*)d_in[21];
    const int* aa0  = (const int*)d_in[22];
    const int* aa1  = (const int*)d_in[23];
    const int* gg0  = (const int*)d_in[24];
    const int* gg1  = (const int*)d_in[25];
    const float* W_emb = (const float*)d_in[26];
    const float* b_emb = (const float*)d_in[27];
    const float* gW_main = (const float*)d_in[28];
    const float* gW_s2m  = (const float*)d_in[29];
    const float* gW_gm   = (const float*)d_in[30];
    const float* gb_gm   = (const float*)d_in[31];
    const float* gW_q    = (const float*)d_in[32];
    const float* gW_k    = (const float*)d_in[33];
    const float* gW_mrg  = (const float*)d_in[34];
    const float* gW_gs   = (const float*)d_in[35];
    const float* gb_gs   = (const float*)d_in[36];
    const float* gm_Wih = (const float*)d_in[37];
    const float* gm_Whh = (const float*)d_in[38];
    const float* gm_bih = (const float*)d_in[39];
    const float* gm_bhh = (const float*)d_in[40];
    const float* gs_Wih = (const float*)d_in[41];
    const float* gs_Whh = (const float*)d_in[42];
    const float* gs_bih = (const float*)d_in[43];
    const float* gs_bhh = (const float*)d_in[44];
    const float* W_s0 = (const float*)d_in[45];
    const float* b_s0 = (const float*)d_in[46];
    const float* W_s1 = (const float*)d_in[47];
    const float* b_s1 = (const float*)d_in[48];
    const float* W_so = (const float*)d_in[49];
    const float* b_so = (const float*)d_in[50];
    const float* W_m0 = (const float*)d_in[51];
    const float* b_m0 = (const float*)d_in[52];
    const float* W_m1 = (const float*)d_in[53];
    const float* b_m1 = (const float*)d_in[54];
    const float* W_mo = (const float*)d_in[55];
    const float* b_mo = (const float*)d_in[56];
    const float* W_a0 = (const float*)d_in[57];
    const float* b_a0 = (const float*)d_in[58];
    const float* W_a1 = (const float*)d_in[59];
    const float* b_a1 = (const float*)d_in[60];
    const float* W_ao = (const float*)d_in[61];
    const float* b_ao = (const float*)d_in[62];
    const float* W_ds = (const float*)d_in[63];
    const float* b_ds = (const float*)d_in[64];
    const float* W_dc = (const float*)d_in[65];
    const float* b_dc = (const float*)d_in[66];

    const int B = 256, NG = 4000, NA = 10000, Ns = 80000, Nm = 80000;
    const int Nv = in_sizes[7];
    const int FV = in_sizes[0] / Nv;
    const int Fs = in_sizes[1] / Ns;
    const int Fm = in_sizes[2] / Nm;
    const int Ev = in_sizes[5], Ec = in_sizes[8], Es = in_sizes[10], Em = in_sizes[12];
    const int Ep = in_sizes[14], Ea = in_sizes[18];
    const int Pag = in_sizes[20], Paa = in_sizes[22], Pgg = in_sizes[24];
    const int D = in_sizes[28] / (HD * HD);

    // ---- workspace layout (floats) --------------------------------------
    float* ws = (float*)d_ws;
    size_t off = 0;
    auto take = [&](size_t n) { size_t o = off; off += n; return o; };
    float* vert  = ws + take((size_t)Nv * HD);
    float* supe  = ws + take((size_t)B * HD);
    float* qsup  = ws + take((size_t)B * HD);
    float* usup  = ws + take((size_t)B * HD);
    float* pool  = ws + take((size_t)B * HD);
    float* msup  = ws + take((size_t)B * HD);
    float* zsup  = ws + take((size_t)B * HD);
    float* gis   = ws + take((size_t)B * 3 * HD);
    float* ghs   = ws + take((size_t)B * 3 * HD);
    float* tsml  = ws + take((size_t)B * HD);
    float* grp   = ws + take((size_t)NG * HD);
    float* site_o = ws + take((size_t)Ns * HD);
    float* masf_o = ws + take((size_t)Nm * HD);
    float* anch  = ws + take((size_t)NA * 2 * HD);
    float* ah1   = ws + take((size_t)NA * HD);
    float* ah2   = ws + take((size_t)NA * HD);
    float* axw   = ws + take((size_t)NA * HD);
    float* aout  = ws + take((size_t)NA * HD);
    float* pa    = ws + take((size_t)NA * HD);
    float* pg    = ws + take((size_t)NG * HD);
    float* score = ws + take((size_t)Nv);
    const size_t NvH = (size_t)Nv * HD, NsH = (size_t)Ns * HD;
    float* T = ws + take(3 * NsH);   // shared temp region

    // ---- CSR arrays (ints), concatenated layout --------------------------
    const int nN[8] = {Nv, NG, Ns, Nm, NA, NA, NA, B};
    const int nE[8] = {Ev, Ec, Es, Em, Ep, Ep, Ea, Nv};
    const int* dsts[8] = {vert_dst, comp_dst, site_dst, masf_dst,
                          prot_dst, prom_dst, anch_dst, vbatch};
    int baseN[9], baseE[9];
    baseN[0] = 0; baseE[0] = 0;
    for (int g = 0; g < 8; ++g) { baseN[g + 1] = baseN[g] + nN[g]; baseE[g + 1] = baseE[g] + nE[g]; }
    const int totN = baseN[8], totE = baseE[8];

    int* ib = (int*)(ws + off);
    size_t ioff = 0;
    auto taki = [&](size_t n) { size_t o = ioff; ioff += n; return o; };
    int* cnt_all = ib + taki((size_t)totN);
    int* rp_all  = ib + taki((size_t)totN + 1);
    int* cur_all = ib + taki((size_t)totN);
    int* ei_all  = ib + taki((size_t)totE);
    int* bsum    = ib + taki((size_t)((totN + SCB - 1) / SCB) + 1);
    ioff = (ioff + 7) & ~(size_t)7;   // 16B-align the bf16 arena

    // ---- bf16 weight arenas ----------------------------------------------
    unsigned short* warena = (unsigned short*)(ib + ioff);
    size_t woff = 0;
    WBatch wb; int nW = 0; long maxWTot = 0;
    auto reg = [&](const float* src, int K, int N, int tr) {
        int Kpad = (K + 31) & ~31;
        unsigned short* dst = warena + woff;
        woff += (size_t)N * Kpad;
        long tot = (long)N * Kpad; if (tot > maxWTot) maxWTot = tot;
        wb.d[nW].src = src; wb.d[nW].dst = dst; wb.d[nW].K = K;
        wb.d[nW].N = N; wb.d[nW].Kpad = Kpad; wb.d[nW].tr = tr;
        ++nW;
        WArena a; a.p = dst; a.Kpad = Kpad; return a;
    };
    WArena wa_emb = reg(W_emb, FV, HD, 1);
    WArena wa_main[2], wa_s2m[2], wa_gm[2], wa_q[2], wa_kT[2], wa_mrg[2], wa_gs[2];
    for (int t = 0; t < D && t < 2; ++t) {
        wa_main[t] = reg(gW_main + (size_t)t * HD * HD, HD, HD, 1);
        wa_s2m[t]  = reg(gW_s2m  + (size_t)t * HD * HD, HD, HD, 1);
        wa_gm[t]   = reg(gW_gm   + (size_t)t * 2 * HD * HD, 2 * HD, HD, 1);
        wa_q[t]    = reg(gW_q    + (size_t)t * HD * HD, HD, HD, 1);
        wa_kT[t]   = reg(gW_k    + (size_t)t * HD * HD, HD, HD, 0);  // u = q @ Wk^T
        wa_mrg[t]  = reg(gW_mrg  + (size_t)t * HD * HD, HD, HD, 1);
        wa_gs[t]   = reg(gW_gs   + (size_t)t * 2 * HD * HD, 2 * HD, HD, 1);
    }
    WArena wa_mih = reg(gm_Wih, HD, 3 * HD, 0);   // GRU: x@Wih.T -> WT = Wih as-is
    WArena wa_mhh = reg(gm_Whh, HD, 3 * HD, 0);
    WArena wa_sih = reg(gs_Wih, HD, 3 * HD, 0);
    WArena wa_shh = reg(gs_Whh, HD, 3 * HD, 0);
    WArena wa_s0 = reg(W_s0, Fs, HD, 1);
    WArena wa_s1 = reg(W_s1, HD, HD, 1);
    WArena wa_so = reg(W_so, Fs + 2 * HD, HD, 1);
    WArena wa_m0 = reg(W_m0, Fm, HD, 1);
    WArena wa_m1 = reg(W_m1, HD, HD, 1);
    WArena wa_mo = reg(W_mo, Fm + 2 * HD, HD, 1);
    WArena wa_a0 = reg(W_a0, 2 * HD, HD, 1);
    WArena wa_a1 = reg(W_a1, HD, HD, 1);
    WArena wa_ao = reg(W_ao, 4 * HD, HD, 1);
    WArena wa_ds = reg(W_ds, HD, HD, 1);
    WArena wa_dc = reg(W_dc, HD, HD, 1);

    if (ws_size < off * sizeof(float) + ioff * sizeof(int) + woff * sizeof(unsigned short))
        return;

    {
        dim3 g((unsigned)((maxWTot + 255) / 256), nW);
        hipLaunchKernelGGL(convert_weights, g, dim3(256), 0, stream, wb);
    }

    // ---- CSR build --------------------------------------------------------
    hipMemsetAsync(cnt_all, 0, (size_t)totN * sizeof(int), stream);
    for (int g = 0; g < 8; ++g)
        hist_k<<<gupd((size_t)nE[g]), 256, 0, stream>>>(cnt_all + baseN[g], dsts[g], nE[g]);
    const int nScanBlocks = (totN + SCB - 1) / SCB;
    scan_sums<<<nScanBlocks, 256, 0, stream>>>(cnt_all, totN, bsum);
    scan_bsum<<<1, 64, 0, stream>>>(bsum, nScanBlocks);
    scan_write<<<nScanBlocks, 256, 0, stream>>>(cnt_all, totN, bsum, rp_all);
    hipMemcpyAsync(cur_all, rp_all, (size_t)totN * sizeof(int), hipMemcpyDeviceToDevice, stream);
    for (int g = 0; g < 8; ++g)
        fill_k<<<gupd((size_t)nE[g]), 256, 0, stream>>>(ei_all, cur_all + baseN[g], dsts[g], nE[g]);

    const int* rp_v = rp_all + baseN[0];
    const int* rp_c = rp_all + baseN[1];
    const int* rp_s = rp_all + baseN[2];
    const int* rp_m = rp_all + baseN[3];
    const int* rp_p = rp_all + baseN[4];
    const int* rp_q = rp_all + baseN[5];
    const int* rp_a = rp_all + baseN[6];
    const int* rp_b = rp_all + baseN[7];
    const int* ei = ei_all;

    // ---- embedding + super-node init ------------------------------------
    gemm1(stream, vert_x, FV, wa_emb, b_emb, vert, Nv, HD, 1);
    seg_gather<<<gup4(B), 256, 0, stream>>>(supe, vert, rp_b, ei, nullptr, nullptr,
                                            nullptr, B, HD, 0, 0, 0);

    // ---- GWM iterations ---------------------------------------------------
    float* Ta = T;            float* Tb = T + NvH;
    float* Td = T + 3 * NvH;  float* Te = T + 4 * NvH; float* Tf = T + 7 * NvH;
    for (int t = 0; t < D; ++t) {
        const float* bgm = gb_gm + (size_t)t * HD;
        const float* bgs = gb_gs + (size_t)t * HD;

        gemm1(stream, vert, HD, wa_main[t], nullptr, Ta, Nv, HD, 0);
        seg_gather<<<gup4((size_t)Nv), 256, 0, stream>>>(Tb, Ta, rp_v, ei, vert_src,
                                                         nullptr, nullptr, Nv, HD, 0, 1, 0);
        gemm1(stream, supe, HD, wa_s2m[t], nullptr, tsml, B, HD, 1);
        // gate gemm with fused trans gather: A1/G2 rows = tsml[vbatch[row]]
        gemm3s(stream, Tb, HD, tsml, HD, nullptr, 0, wa_gm[t], bgm, Td, Nv, HD, 3,
               Tb, tsml, vbatch, 1);
        gemm1(stream, Td, HD, wa_mih, gm_bih, Te, Nv, 3 * HD, 0);
        gemm1(stream, vert, HD, wa_mhh, gm_bhh, Tf, Nv, 3 * HD, 0);
        gru_gate<<<gupd(NvH), 256, 0, stream>>>(vert, Te, Tf, Nv);
        // attention: u_b = (supe@Wq) @ Wk^T  (tiny), score = vert . u[batch]
        gemm1(stream, supe, HD, wa_q[t], nullptr, qsup, B, HD, 0);
        gemm1(stream, qsup, HD, wa_kT[t], nullptr, usup, B, HD, 0);
        dot_score<<<gupd((size_t)Nv), 256, 0, stream>>>(score, vert, usup, vbatch, Nv);
        seg_softmax_csr<<<gup4(B), 256, 0, stream>>>(score, rp_b, ei, B);
        seg_gather<<<gup4(B), 256, 0, stream>>>(pool, vert, rp_b, ei, nullptr, score,
                                                nullptr, B, HD, 0, 0, 1);
        gemm1(stream, pool, HD, wa_mrg[t], nullptr, msup, B, HD, 1);
        gemm3s(stream, msup, HD, supe, HD, nullptr, 0, wa_gs[t], bgs, zsup, B, HD, 3,
               msup, supe, nullptr, 0);
        gemm1(stream, zsup, HD, wa_sih, gs_bih, gis, B, 3 * HD, 0);
        gemm1(stream, supe, HD, wa_shh, gs_bhh, ghs, B, 3 * HD, 0);
        gru_gate<<<gupd((size_t)B * HD), 256, 0, stream>>>(supe, gis, ghs, B);
    }

    // ---- Group module ------------------------------------------------------
    seg_gather<<<gup4((size_t)NG), 256, 0, stream>>>(grp, vert, rp_c, ei, comp_src,
                                                     nullptr, nullptr, NG, HD, 0, 0, 2);

    // ---- site conv stack ---------------------------------------------------
    float* T1 = T; float* T2 = T + NsH; float* T3 = T + 2 * NsH;
    gemm1(stream, site_x, Fs, wa_s0, nullptr, T1, Ns, HD, 0);
    seg_gather<<<gup4((size_t)Ns), 256, 0, stream>>>(T2, T1, rp_s, ei, site_src,
                                                     nullptr, b_s0, Ns, HD, 0, 1, 0);
    gemm1(stream, T2, HD, wa_s1, nullptr, T1, Ns, HD, 0);
    seg_gather<<<gup4((size_t)Ns), 256, 0, stream>>>(T3, T1, rp_s, ei, site_src,
                                                     nullptr, b_s1, Ns, HD, 0, 1, 0);
    gemm3s(stream, site_x, Fs, T2, HD, T3, HD, wa_so, b_so, site_o, Ns, HD, 1);

    // ---- masf conv stack ---------------------------------------------------
    gemm1(stream, masf_x, Fm, wa_m0, nullptr, T1, Nm, HD, 0);
    seg_gather<<<gup4((size_t)Nm), 256, 0, stream>>>(T2, T1, rp_m, ei, masf_src,
                                                     nullptr, b_m0, Nm, HD, 0, 1, 0);
    gemm1(stream, T2, HD, wa_m1, nullptr, T1, Nm, HD, 0);
    seg_gather<<<gup4((size_t)Nm), 256, 0, stream>>>(T3, T1, rp_m, ei, masf_src,
                                                     nullptr, b_m1, Nm, HD, 0, 1, 0);
    gemm3s(stream, masf_x, Fm, T2, HD, T3, HD, wa_mo, b_mo, masf_o, Nm, HD, 1);

    // ---- anchor pooling ----------------------------------------------------
    seg_gather<<<gup4((size_t)NA), 256, 0, stream>>>(anch, site_o, rp_p, ei, prot_src,
                                                     prot_ea, nullptr, NA, 2 * HD, 0, 0, 3);
    seg_gather<<<gup4((size_t)NA), 256, 0, stream>>>(anch, masf_o, rp_q, ei, prom_src,
                                                     prom_ea, nullptr, NA, 2 * HD, HD, 0, 3);

    // ---- anchor conv stack -------------------------------------------------
    gemm1(stream, anch, 2 * HD, wa_a0, nullptr, axw, NA, HD, 0);
    seg_gather<<<gup4((size_t)NA), 256, 0, stream>>>(ah1, axw, rp_a, ei, anch_src,
                                                     nullptr, b_a0, NA, HD, 0, 1, 0);
    gemm1(stream, ah1, HD, wa_a1, nullptr, axw, NA, HD, 0);
    seg_gather<<<gup4((size_t)NA), 256, 0, stream>>>(ah2, axw, rp_a, ei, anch_src,
                                                     nullptr, b_a1, NA, HD, 0, 1, 0);
    gemm3s(stream, anch, 2 * HD, ah1, HD, ah2, HD, wa_ao, b_ao, aout, NA, HD, 1);

    // ---- distance heads ----------------------------------------------------
    gemm1(stream, aout, HD, wa_ds, b_ds, pa, NA, HD, 1);
    gemm1(stream, grp, HD, wa_dc, b_dc, pg, NG, HD, 1);
    float* outp = (float*)d_out;
    pdist_k<<<gupd((size_t)Pag), 256, 0, stream>>>(outp, pa, pg, ag_a, ag_g, Pag);
    pdist_k<<<gupd((size_t)Paa), 256, 0, stream>>>(outp + Pag, pa, pa, aa0, aa1, Paa);
    pdist_k<<<gupd((size_t)Pgg), 256, 0, stream>>>(outp + Pag + Paa, pg, pg, gg0, gg1, Pgg);
}